// Round 8
// baseline (794.778 us; speedup 1.0000x reference)
//
#include <hip/hip_runtime.h>
#include <stdint.h>

#define B_  4
#define S_  4096
#define D_  1024
#define H_  16
#define R_  256
#define HD_ 64
#define BH_ 64        // B_*H_
#define M_  16384     // B_*S_
#define SPLITK_ 8     // kv split-K partials, bf16: 8*64*256*80*2 = 21 MB <= x_lo (33.5 MB)

typedef uint16_t u16;
typedef __attribute__((ext_vector_type(8))) short short8;
typedef __attribute__((ext_vector_type(4))) float f32x4;
typedef __attribute__((ext_vector_type(4))) unsigned short us4;

__device__ __forceinline__ u16 f2bf(float f){
  union { float f; uint32_t u; } v; v.f = f;
  uint32_t r = v.u + 0x7FFFu + ((v.u >> 16) & 1u);
  return (u16)(r >> 16);
}
__device__ __forceinline__ float bf2f(u16 h){
  union { uint32_t u; float f; } v; v.u = ((uint32_t)h) << 16;
  return v.f;
}
__device__ __forceinline__ f32x4 mfma16(short8 a, short8 b, f32x4 c){
  return __builtin_amdgcn_mfma_f32_16x16x32_bf16(a, b, c, 0, 0, 0);
}
// async global->LDS DMA, 16B per lane; LDS dest = wave-uniform base + lane*16,
// global source address is PER-LANE (enables pre-swizzled staging, rule #21)
__device__ __forceinline__ void gl_lds16(const u16* g, u16* l){
  __builtin_amdgcn_global_load_lds((const __attribute__((address_space(1))) void*)g,
                                   (__attribute__((address_space(3))) void*)l, 16, 0, 0);
}
// split a float8 (two float4) into bf16 hi + lo fragments
__device__ __forceinline__ void cvt8(const float4& a, const float4& b, short8& hi, short8& lo){
  float f[8] = {a.x,a.y,a.z,a.w,b.x,b.y,b.z,b.w};
  #pragma unroll
  for (int j=0;j<8;j++){
    u16 h = f2bf(f[j]);
    hi[j] = (short)h;
    lo[j] = (short)f2bf(f[j] - bf2f(h));
  }
}

// Stage rf_hi/rf_lo for one head into LDS [256 rows][8 groups of 16B], with the
// bank-swizzle gs = gd ^ (row&7) applied on the GLOBAL source address (LDS dest
// stays linear, as global_load_lds requires). Read side XORs the same way.
// NTH = block thread count (256 or 512).
template<int NTH>
__device__ __forceinline__ void stage_rf(const u16* __restrict__ rfh,
                                         const u16* __restrict__ rfl,
                                         int h, int tid, u16* lrfh, u16* lrfl){
  const u16* baseH = rfh + (size_t)h*(R_*HD_);
  const u16* baseL = rfl + (size_t)h*(R_*HD_);
  const int wbase = tid & ~63;        // wave-uniform thread base
  #pragma unroll
  for (int c=0;c<2048/NTH;c++){
    int idx = c*NTH + tid;            // 0..2047 <-> (row 0..255, group 0..7)
    int row = idx >> 3, gd = idx & 7;
    int gs  = gd ^ (row & 7);         // inverse swizzle on source
    gl_lds16(baseH + row*64 + gs*8, lrfh + (size_t)(c*NTH + wbase)*8);
    gl_lds16(baseL + row*64 + gs*8, lrfl + (size_t)(c*NTH + wbase)*8);
  }
}

// ---------------- prep kernels ----------------
__global__ void split_kernel(const float* __restrict__ src, u16* __restrict__ hi,
                             u16* __restrict__ lo, int n4){
  int i = blockIdx.x*blockDim.x + threadIdx.x;
  if (i >= n4) return;
  float4 f = ((const float4*)src)[i];
  float ff[4] = {f.x,f.y,f.z,f.w};
  us4 hv, lv;
  #pragma unroll
  for (int j=0;j<4;j++){
    u16 h = f2bf(ff[j]);
    hv[j] = h;
    lv[j] = f2bf(ff[j] - bf2f(h));
  }
  ((us4*)hi)[i] = hv;
  if (lo) ((us4*)lo)[i] = lv;
}

// rf [H][HD][R] fp32 -> rf_t hi/lo [H][R][HD] bf16
__global__ void rf_split_kernel(const float* __restrict__ rf, u16* __restrict__ rhi,
                                u16* __restrict__ rlo){
  int idx = blockIdx.x*256 + threadIdx.x;     // over H*R*HD = 262144
  int d = idx & 63, r = (idx >> 6) & 255, h = idx >> 14;
  float f = rf[((size_t)h*HD_ + d)*R_ + r];
  u16 hh = f2bf(f);
  rhi[idx] = hh;
  rlo[idx] = f2bf(f - bf2f(hh));
}

// fused ||row||^2/2: lane (q,rr) holds 16 elems of row w*16+rr.
// result sql[r4] = 0.5*||row w*16+q*4+r4||^2 on every lane (matches C-layout rows).
__device__ __forceinline__ void rowsq(const float4& x0, const float4& x1,
                                      const float4& x2, const float4& x3,
                                      int q, float sql[4]){
  float s = x0.x*x0.x + x0.y*x0.y + x0.z*x0.z + x0.w*x0.w
          + x1.x*x1.x + x1.y*x1.y + x1.z*x1.z + x1.w*x1.w
          + x2.x*x2.x + x2.y*x2.y + x2.z*x2.z + x2.w*x2.w
          + x3.x*x3.x + x3.y*x3.y + x3.z*x3.z + x3.w*x3.w;
  s += __shfl_xor(s, 16);
  s += __shfl_xor(s, 32);
  #pragma unroll
  for (int r4=0;r4<4;r4++) sql[r4] = 0.5f * __shfl(s, q*4 + r4);
}

// ---------------- 128x128 MFMA GEMM, K=1024, A[M][K], B[N][K] (both bf16) ----------------
// Staging: global_load_lds width=16 (m97 pattern, 2-barrier K-loop).
// LDS chunk layout (1 KB per 16 rows x 32 k): lane l -> row c*16+(l>>2), pos p=l&3;
// pos p holds global 16B-group g = p ^ ((row>>1)&3)  (XOR swizzle -> free 2-way reads)
// NSPLIT==3: acc += Ah*Bh + Ah*Bl + Al*Bh   (split-bf16 ~fp32 precision)
// EPI 0: fp32 -> [b,h,s,hd]+bias | EPI 1: bf16 -> [b,h,hd,s]+bias | EPI 2: fp32 [m][n]+bias
template<int NSPLIT, int EPI>
__global__ __launch_bounds__(256, 2)
void gemm128(const u16* __restrict__ Ah, const u16* __restrict__ Al,
             const u16* __restrict__ Bh, const u16* __restrict__ Bl,
             const float* __restrict__ bias, float* __restrict__ outF,
             u16* __restrict__ outB){
  constexpr int NBUF = (NSPLIT==3) ? 4 : 2;
  __shared__ u16 lds[NBUF * 4096];
  const int tid = threadIdx.x, w = tid >> 6, lane = tid & 63;
  const int wm = w & 1, wn = w >> 1;
  const int m0 = blockIdx.x * 128, n0 = blockIdx.y * 128;
  const int q = lane >> 4, rr = lane & 15;

  const int c0 = w*2, c1 = w*2 + 1;
  const int row0 = c0*16 + (lane >> 2), row1 = c1*16 + (lane >> 2);
  const int g0 = (lane & 3) ^ ((row0 >> 1) & 3);
  const int g1 = (lane & 3) ^ ((row1 >> 1) & 3);
  const size_t a0 = (size_t)(m0 + row0)*1024 + g0*8;
  const size_t a1 = (size_t)(m0 + row1)*1024 + g1*8;
  const size_t b0 = (size_t)(n0 + row0)*1024 + g0*8;
  const size_t b1 = (size_t)(n0 + row1)*1024 + g1*8;

  f32x4 acc[4][4];
  #pragma unroll
  for (int i=0;i<4;i++)
    #pragma unroll
    for (int j=0;j<4;j++) acc[i][j] = f32x4{0.f,0.f,0.f,0.f};

  for (int kt=0; kt<32; kt++){
    const int k0 = kt*32;
    gl_lds16(Ah + a0 + k0, lds + 0*4096 + c0*512);
    gl_lds16(Ah + a1 + k0, lds + 0*4096 + c1*512);
    gl_lds16(Bh + b0 + k0, lds + 1*4096 + c0*512);
    gl_lds16(Bh + b1 + k0, lds + 1*4096 + c1*512);
    if constexpr (NSPLIT == 3){
      gl_lds16(Al + a0 + k0, lds + 2*4096 + c0*512);
      gl_lds16(Al + a1 + k0, lds + 2*4096 + c1*512);
      gl_lds16(Bl + b0 + k0, lds + 3*4096 + c0*512);
      gl_lds16(Bl + b1 + k0, lds + 3*4096 + c1*512);
    }
    __syncthreads();   // drains vmcnt -> staged data visible

    short8 afh[4], bfh[4], afl[4], bfl[4];
    #pragma unroll
    for (int i=0;i<4;i++){
      int r  = wm*64 + i*16 + rr;
      int o  = r*32 + ((q ^ ((r >> 1) & 3))*8);
      afh[i] = *(const short8*)(lds + 0*4096 + o);
      if constexpr (NSPLIT == 3) afl[i] = *(const short8*)(lds + 2*4096 + o);
      int rn = wn*64 + i*16 + rr;
      int on = rn*32 + ((q ^ ((rn >> 1) & 3))*8);
      bfh[i] = *(const short8*)(lds + 1*4096 + on);
      if constexpr (NSPLIT == 3) bfl[i] = *(const short8*)(lds + 3*4096 + on);
    }
    #pragma unroll
    for (int i=0;i<4;i++)
      #pragma unroll
      for (int j=0;j<4;j++){
        acc[i][j] = mfma16(afh[i], bfh[j], acc[i][j]);
        if constexpr (NSPLIT == 3){
          acc[i][j] = mfma16(afh[i], bfl[j], acc[i][j]);
          acc[i][j] = mfma16(afl[i], bfh[j], acc[i][j]);
        }
      }
    __syncthreads();   // protect LDS from next kt's DMA
  }

  #pragma unroll
  for (int i=0;i<4;i++){
    #pragma unroll
    for (int j=0;j<4;j++){
      int n  = n0 + wn*64 + j*16 + rr;
      float bb = bias[n];
      if constexpr (EPI == 1){
        int mb = m0 + wm*64 + i*16 + q*4;
        us4 pk;
        #pragma unroll
        for (int r4=0;r4<4;r4++) pk[r4] = f2bf(acc[i][j][r4] + bb);
        *(us4*)(outB + ((size_t)((mb >> 12)*H_ + (n >> 6))*HD_ + (n & 63))*S_ + (mb & 4095)) = pk;
      } else {
        #pragma unroll
        for (int r4=0;r4<4;r4++){
          int m = m0 + wm*64 + i*16 + q*4 + r4;
          float v = acc[i][j][r4] + bb;
          if constexpr (EPI == 0)
            outF[((size_t)((m >> 12)*H_ + (n >> 6)))*S_*HD_ + (size_t)(m & 4095)*HD_ + (n & 63)] = v;
          else
            outF[(size_t)m*1024 + n] = v;
        }
      }
    }
  }
}

// ---------------- fused k-feature + kv' split-K partial ----------------
// grid (SPLITK_, BH_); block covers 512 s rows, 8 sub-chunks of 64.  (R6-exact)
// rf_hi+rf_lo staged in LDS once per block (64 KB, XOR-swizzled source, rule #21).
// LDS total 36.9+64 = 102.4 KB -> 1 block/CU.
__global__ __launch_bounds__(256, 1)
void kfeat_kv_kernel(const float* __restrict__ k32,
                     const u16* __restrict__ rfh, const u16* __restrict__ rfl,
                     const u16* __restrict__ vt, u16* __restrict__ kvp16){
  __shared__ u16 kp[R_*72];
  __shared__ u16 lrfh[R_*HD_];
  __shared__ u16 lrfl[R_*HD_];
  const int sp = blockIdx.x, hb = blockIdx.y, h = hb & 15;
  const int tid = threadIdx.x, w = tid >> 6, lane = tid & 63;
  const int q = lane >> 4, rr = lane & 15;
  const int sw8 = rr & 7;

  stage_rf<256>(rfh, rfl, h, tid, lrfh, lrfl);

  short8 ones;
  { u16 one = (rr == 0) ? (u16)0x3F80 : (u16)0;
    #pragma unroll
    for (int j=0;j<8;j++) ones[j] = (short)one; }

  f32x4 acc2[4][5];
  #pragma unroll
  for (int a=0;a<4;a++)
    #pragma unroll
    for (int t=0;t<5;t++) acc2[a][t] = f32x4{0.f,0.f,0.f,0.f};

  __syncthreads();   // rf staged (drains DMA)

  // preload sub 0's k rows
  const float* ap0 = k32 + ((size_t)hb*S_ + sp*(S_/SPLITK_) + w*16 + rr)*HD_ + q*8;
  float4 x0 = *(const float4*)(ap0);
  float4 x1 = *(const float4*)(ap0 + 4);
  float4 x2 = *(const float4*)(ap0 + 32);
  float4 x3 = *(const float4*)(ap0 + 36);

  for (int sub=0; sub<(S_/SPLITK_)/64; sub++){
    const int s0 = sp*(S_/SPLITK_) + sub*64;
    float sql[4];
    rowsq(x0, x1, x2, x3, q, sql);
    short8 ah[2], al[2];
    cvt8(x0, x1, ah[0], al[0]);
    cvt8(x2, x3, ah[1], al[1]);
    if (sub < (S_/SPLITK_)/64 - 1){   // prefetch next sub's k rows
      const float* apn = k32 + ((size_t)hb*S_ + s0 + 64 + w*16 + rr)*HD_ + q*8;
      x0 = *(const float4*)(apn);
      x1 = *(const float4*)(apn + 4);
      x2 = *(const float4*)(apn + 32);
      x3 = *(const float4*)(apn + 36);
    }

    f32x4 accp[16];
    #pragma unroll
    for (int t=0;t<16;t++) accp[t] = f32x4{0.f,0.f,0.f,0.f};
    #pragma unroll
    for (int t=0;t<16;t++){
      const u16* lrow  = lrfh + (t*16 + rr)*64;
      const u16* lrowl = lrfl + (t*16 + rr)*64;
      short8 bh0 = *(const short8*)(lrow  + ((q     ^ sw8))*8);
      short8 bh1 = *(const short8*)(lrow  + (((q+4) ^ sw8))*8);
      short8 bl0 = *(const short8*)(lrowl + ((q     ^ sw8))*8);
      short8 bl1 = *(const short8*)(lrowl + (((q+4) ^ sw8))*8);
      f32x4 c = accp[t];
      c = mfma16(ah[0], bh0, c); c = mfma16(ah[0], bl0, c); c = mfma16(al[0], bh0, c);
      c = mfma16(ah[1], bh1, c); c = mfma16(ah[1], bl1, c); c = mfma16(al[1], bh1, c);
      accp[t] = c;
    }
    #pragma unroll
    for (int t=0;t<16;t++){
      us4 pk;
      #pragma unroll
      for (int r4=0;r4<4;r4++) pk[r4] = f2bf(__expf(accp[t][r4] - sql[r4]));
      *(us4*)(kp + (t*16 + rr)*72 + w*16 + q*4) = pk;
    }
    __syncthreads();
    #pragma unroll
    for (int ks=0; ks<2; ks++){
      short8 af[4];
      #pragma unroll
      for (int a=0;a<4;a++)
        af[a] = *(const short8*)(kp + (w*64 + a*16 + rr)*72 + ks*32 + q*8);
      #pragma unroll
      for (int t=0;t<5;t++){
        short8 bf;
        if (t < 4)
          bf = *(const short8*)(vt + ((size_t)hb*HD_ + t*16 + rr)*S_ + s0 + ks*32 + q*8);
        else
          bf = ones;
        #pragma unroll
        for (int a=0;a<4;a++) acc2[a][t] = mfma16(af[a], bf, acc2[a][t]);
      }
    }
    __syncthreads();
  }
  u16* op = kvp16 + ((size_t)hb*SPLITK_ + sp)*R_*80;
  #pragma unroll
  for (int a=0;a<4;a++)
    #pragma unroll
    for (int t=0;t<5;t++)
      #pragma unroll
      for (int r4=0;r4<4;r4++){
        int r = w*64 + a*16 + q*4 + r4;
        int c = t*16 + rr;
        op[r*80 + c] = f2bf(acc2[a][t][r4]);
      }
}

// reduce bf16 kv partials: kv_t[hb][d][r] bf16, ksum[hb][r] fp32
__global__ void kv_reduce_kernel(const u16* __restrict__ kvp16, u16* __restrict__ kvt,
                                 float* __restrict__ ksum){
  int r = blockIdx.x, hb = blockIdx.y, c = threadIdx.x;
  if (c >= 65) return;
  const u16* base = kvp16 + (size_t)hb*SPLITK_*R_*80 + r*80 + c;
  float s = 0.f;
  #pragma unroll
  for (int sp=0; sp<SPLITK_; sp++) s += bf2f(base[(size_t)sp*R_*80]);
  if (c < 64) kvt[((size_t)hb*HD_ + c)*R_ + r] = f2bf(s);
  else        ksum[(size_t)hb*R_ + r] = s;
}

// ---------------- fused q-feature + attn + norm ----------------
// grid (8, BH_); 512-THREAD block (8 waves) covers 512 s rows, 4 sub-chunks of 128.
// Key change vs R6: the per-block rf staging (64 KB LDS) is now shared by 8 waves
// instead of 4 -> 2 waves/SIMD BY BLOCK SHAPE (1 block/CU, LDS 67.6+64 = 131.6 KB),
// doubling latency hiding without asking the register allocator for anything:
// __launch_bounds__(512,1) caps VGPR at 256 = the natural allocation R5-R7 chose.
// qp is wave-private (wave w owns rows w*16..w*16+15) -> no barriers in sub loop.
__global__ __launch_bounds__(512, 1)
void qfeat_attn_kernel(const float* __restrict__ q32,
                       const u16* __restrict__ rfh, const u16* __restrict__ rfl,
                       const u16* __restrict__ kvt, const float* __restrict__ ksum,
                       u16* __restrict__ attn_c){
  __shared__ u16 qp[128*264];
  __shared__ u16 lrfh[R_*HD_];
  __shared__ u16 lrfl[R_*HD_];
  const int sc8 = blockIdx.x, hb = blockIdx.y, h = hb & 15, b = hb >> 4;
  const int tid = threadIdx.x, w = tid >> 6, lane = tid & 63;
  const int q = lane >> 4, rr = lane & 15;
  const int sw8 = rr & 7;

  stage_rf<512>(rfh, rfl, h, tid, lrfh, lrfl);

  float kslv[16];
  #pragma unroll
  for (int t=0;t<16;t++) kslv[t] = ksum[(size_t)hb*R_ + t*16 + rr];

  __syncthreads();   // rf staged (drains DMA)

  // preload sub 0's q rows
  const float* ap0 = q32 + ((size_t)hb*S_ + sc8*512 + w*16 + rr)*HD_ + q*8;
  float4 x0 = *(const float4*)(ap0);
  float4 x1 = *(const float4*)(ap0 + 4);
  float4 x2 = *(const float4*)(ap0 + 32);
  float4 x3 = *(const float4*)(ap0 + 36);

  for (int sub=0; sub<4; sub++){
    const int s0 = sc8*512 + sub*128;
    // ---- phase 1: q' for 128 s rows (16 per wave) ----
    float sql[4];
    rowsq(x0, x1, x2, x3, q, sql);
    short8 ah[2], al[2];
    cvt8(x0, x1, ah[0], al[0]);
    cvt8(x2, x3, ah[1], al[1]);
    if (sub < 3){   // prefetch next sub's q rows (completes under phase 1+2)
      const float* apn = q32 + ((size_t)hb*S_ + s0 + 128 + w*16 + rr)*HD_ + q*8;
      x0 = *(const float4*)(apn);
      x1 = *(const float4*)(apn + 4);
      x2 = *(const float4*)(apn + 32);
      x3 = *(const float4*)(apn + 36);
    }

    f32x4 accp[16];
    #pragma unroll
    for (int t=0;t<16;t++) accp[t] = f32x4{0.f,0.f,0.f,0.f};
    #pragma unroll
    for (int t=0;t<16;t++){
      const u16* lrow  = lrfh + (t*16 + rr)*64;
      const u16* lrowl = lrfl + (t*16 + rr)*64;
      short8 bh0 = *(const short8*)(lrow  + ((q     ^ sw8))*8);
      short8 bh1 = *(const short8*)(lrow  + (((q+4) ^ sw8))*8);
      short8 bl0 = *(const short8*)(lrowl + ((q     ^ sw8))*8);
      short8 bl1 = *(const short8*)(lrowl + (((q+4) ^ sw8))*8);
      f32x4 c = accp[t];
      c = mfma16(ah[0], bh0, c); c = mfma16(ah[0], bl0, c); c = mfma16(al[0], bh0, c);
      c = mfma16(ah[1], bh1, c); c = mfma16(ah[1], bl1, c); c = mfma16(al[1], bh1, c);
      accp[t] = c;
    }
    // exp -> qp (A-layout staging, wave-private rows) + in-register norm partials
    float npl[4] = {0.f, 0.f, 0.f, 0.f};
    #pragma unroll
    for (int t=0;t<16;t++){
      us4 pk;
      #pragma unroll
      for (int r4=0;r4<4;r4++){
        float e = __expf(accp[t][r4] - sql[r4]);
        npl[r4] += e * kslv[t];
        pk[r4] = f2bf(e);
      }
      #pragma unroll
      for (int r4=0;r4<4;r4++)
        qp[(w*16 + q*4 + r4)*264 + t*16 + rr] = pk[r4];
    }
    // reduce norm over rr (bits 0-3 of lane) -> lanes keep rows q*4+r4
    #pragma unroll
    for (int r4=0;r4<4;r4++){
      npl[r4] += __shfl_xor(npl[r4], 1);
      npl[r4] += __shfl_xor(npl[r4], 2);
      npl[r4] += __shfl_xor(npl[r4], 4);
      npl[r4] += __shfl_xor(npl[r4], 8);
    }
    // no barrier: qp rows read below are the ones this wave just wrote (in-order DS)

    // ---- phase 2: attn = q' @ kv'^T ; wave w owns s rows w*16..w*16+15 ----
    f32x4 acc[4];
    #pragma unroll
    for (int t=0;t<4;t++) acc[t] = f32x4{0.f,0.f,0.f,0.f};
    #pragma unroll
    for (int ks=0; ks<8; ks++){
      short8 af = *(const short8*)(qp + (w*16 + rr)*264 + ks*32 + q*8);
      #pragma unroll
      for (int t=0;t<4;t++){
        short8 bf = *(const short8*)(kvt + ((size_t)hb*HD_ + t*16 + rr)*R_ + ks*32 + q*8);
        acc[t] = mfma16(af, bf, acc[t]);
      }
    }

    #pragma unroll
    for (int t=0;t<4;t++)
      #pragma unroll
      for (int r4=0;r4<4;r4++){
        int sl = w*16 + q*4 + r4;
        int d  = t*16 + rr;
        float o = acc[t][r4] / (npl[r4] + 1e-6f);
        attn_c[((size_t)b*S_ + s0 + sl)*D_ + h*HD_ + d] = f2bf(o);
      }
    // no trailing barrier: next sub's qp writes are same-wave, in-order
  }
}

// ---------------- host ----------------
extern "C" void kernel_launch(void* const* d_in, const int* in_sizes, int n_in,
                              void* d_out, int out_size, void* d_ws, size_t ws_size,
                              hipStream_t stream){
  (void)in_sizes; (void)n_in; (void)out_size; (void)ws_size;
  const float* x  = (const float*)d_in[0];
  const float* wq = (const float*)d_in[1];
  const float* bq = (const float*)d_in[2];
  const float* wk = (const float*)d_in[3];
  const float* bk = (const float*)d_in[4];
  const float* wv = (const float*)d_in[5];
  const float* bv = (const float*)d_in[6];
  const float* wo = (const float*)d_in[7];
  const float* bo = (const float*)d_in[8];
  const float* rf = (const float*)d_in[9];
  float* out = (float*)d_out;

  char* p = (char*)d_ws;
  size_t off = 0;
  auto take = [&](size_t bytes)->char*{
    char* r = p + off; off += (bytes + 255) & ~(size_t)255; return r;
  };
  u16*  x_hi  = (u16*)take((size_t)M_*D_*2);
  u16*  x_lo  = (u16*)take((size_t)M_*D_*2);
  u16*  wq_hi = (u16*)take((size_t)D_*D_*2);
  u16*  wq_lo = (u16*)take((size_t)D_*D_*2);
  u16*  wk_hi = (u16*)take((size_t)D_*D_*2);
  u16*  wk_lo = (u16*)take((size_t)D_*D_*2);
  u16*  wv_hi = (u16*)take((size_t)D_*D_*2);
  u16*  wo_hi = (u16*)take((size_t)D_*D_*2);
  u16*  rf_hi = (u16*)take((size_t)H_*R_*HD_*2);
  u16*  rf_lo = (u16*)take((size_t)H_*R_*HD_*2);
  float* q32  = (float*)take((size_t)M_*D_*4);
  float* k32  = (float*)take((size_t)M_*D_*4);
  u16*  v_t   = (u16*)take((size_t)M_*D_*2);
  u16*  kvt   = (u16*)take((size_t)BH_*HD_*R_*2);
  float* ksum = (float*)take((size_t)BH_*R_*4);
  // aliases (stream-ordered reuse of dead buffers):
  u16* attn_c = x_hi;   // x_hi dead after V projection
  u16* kvp16  = x_lo;   // x_lo dead after K projection; 21 MB <= 33.5 MB

  // prep: splits
  split_kernel<<<dim3((M_*D_)/1024), 256, 0, stream>>>(x,  x_hi,  x_lo,  (M_*D_)/4);
  split_kernel<<<dim3((D_*D_)/1024), 256, 0, stream>>>(wq, wq_hi, wq_lo, (D_*D_)/4);
  split_kernel<<<dim3((D_*D_)/1024), 256, 0, stream>>>(wk, wk_hi, wk_lo, (D_*D_)/4);
  split_kernel<<<dim3((D_*D_)/1024), 256, 0, stream>>>(wv, wv_hi, nullptr, (D_*D_)/4);
  split_kernel<<<dim3((D_*D_)/1024), 256, 0, stream>>>(wo, wo_hi, nullptr, (D_*D_)/4);
  rf_split_kernel<<<dim3((H_*R_*HD_)/256), 256, 0, stream>>>(rf, rf_hi, rf_lo);

  // projections
  gemm128<3,0><<<dim3(M_/128, D_/128), 256, 0, stream>>>(x_hi, x_lo, wq_hi, wq_lo, bq, q32, nullptr);
  gemm128<3,0><<<dim3(M_/128, D_/128), 256, 0, stream>>>(x_hi, x_lo, wk_hi, wk_lo, bk, k32, nullptr);
  gemm128<1,1><<<dim3(M_/128, D_/128), 256, 0, stream>>>(x_hi, nullptr, wv_hi, nullptr, bv, nullptr, v_t);

  // k' -> kv partials -> reduce
  kfeat_kv_kernel<<<dim3(SPLITK_, BH_), 256, 0, stream>>>(k32, rf_hi, rf_lo, v_t, kvp16);
  kv_reduce_kernel<<<dim3(R_, BH_), 128, 0, stream>>>(kvp16, kvt, ksum);

  // q' -> attn -> attn_c
  qfeat_attn_kernel<<<dim3(8, BH_), 512, 0, stream>>>(q32, rf_hi, rf_lo, kvt, ksum, attn_c);

  // output projection
  gemm128<1,2><<<dim3(M_/128, D_/128), 256, 0, stream>>>(attn_c, nullptr, wo_hi, nullptr, bo, out, nullptr);
}

// Round 9
// 612.543 us; speedup vs baseline: 1.2975x; 1.2975x over previous
//
#include <hip/hip_runtime.h>
#include <stdint.h>

#define B_  4
#define S_  4096
#define D_  1024
#define H_  16
#define R_  256
#define HD_ 64
#define BH_ 64        // B_*H_
#define M_  16384     // B_*S_
#define SPLITK_ 8     // kv split-K partials, bf16: 8*64*256*80*2 = 21 MB <= x_lo (33.5 MB)

typedef uint16_t u16;
typedef __attribute__((ext_vector_type(8))) short short8;
typedef __attribute__((ext_vector_type(4))) float f32x4;
typedef __attribute__((ext_vector_type(4))) unsigned short us4;

__device__ __forceinline__ u16 f2bf(float f){
  union { float f; uint32_t u; } v; v.f = f;
  uint32_t r = v.u + 0x7FFFu + ((v.u >> 16) & 1u);
  return (u16)(r >> 16);
}
__device__ __forceinline__ float bf2f(u16 h){
  union { uint32_t u; float f; } v; v.u = ((uint32_t)h) << 16;
  return v.f;
}
__device__ __forceinline__ f32x4 mfma16(short8 a, short8 b, f32x4 c){
  return __builtin_amdgcn_mfma_f32_16x16x32_bf16(a, b, c, 0, 0, 0);
}
// async global->LDS DMA, 16B per lane; LDS dest = wave-uniform base + lane*16,
// global source address is PER-LANE (enables pre-swizzled staging, rule #21)
__device__ __forceinline__ void gl_lds16(const u16* g, u16* l){
  __builtin_amdgcn_global_load_lds((const __attribute__((address_space(1))) void*)g,
                                   (__attribute__((address_space(3))) void*)l, 16, 0, 0);
}
// split a float8 (two float4) into bf16 hi + lo fragments
__device__ __forceinline__ void cvt8(const float4& a, const float4& b, short8& hi, short8& lo){
  float f[8] = {a.x,a.y,a.z,a.w,b.x,b.y,b.z,b.w};
  #pragma unroll
  for (int j=0;j<8;j++){
    u16 h = f2bf(f[j]);
    hi[j] = (short)h;
    lo[j] = (short)f2bf(f[j] - bf2f(h));
  }
}

// Stage rf_hi/rf_lo (full 256 rows) for one head into LDS, bank-swizzle
// gs = gd ^ (row&7) applied on the GLOBAL source address (LDS dest stays linear,
// rule #21). Read side XORs the same way. 256-thread blocks.
__device__ __forceinline__ void stage_rf_full(const u16* __restrict__ rfh,
                                              const u16* __restrict__ rfl,
                                              int h, int tid, int w,
                                              u16* lrfh, u16* lrfl){
  const u16* baseH = rfh + (size_t)h*(R_*HD_);
  const u16* baseL = rfl + (size_t)h*(R_*HD_);
  #pragma unroll
  for (int c=0;c<8;c++){
    int idx = c*256 + tid;            // 0..2047 <-> (row 0..255, group 0..7)
    int row = idx >> 3, gd = idx & 7;
    int gs  = gd ^ (row & 7);         // inverse swizzle on source
    gl_lds16(baseH + row*64 + gs*8, lrfh + c*2048 + w*512);
    gl_lds16(baseL + row*64 + gs*8, lrfl + c*2048 + w*512);
  }
}

// Stage a 128-row HALF of rf_hi/rf_lo (rows [th*128, th*128+128)), same swizzle.
__device__ __forceinline__ void stage_rf_half(const u16* __restrict__ rfh,
                                              const u16* __restrict__ rfl,
                                              int h, int th, int tid, int w,
                                              u16* lrfh, u16* lrfl){
  const u16* baseH = rfh + (size_t)h*(R_*HD_) + (size_t)th*128*HD_;
  const u16* baseL = rfl + (size_t)h*(R_*HD_) + (size_t)th*128*HD_;
  #pragma unroll
  for (int c=0;c<4;c++){
    int idx = c*256 + tid;            // 0..1023 <-> (row 0..127, group 0..7)
    int row = idx >> 3, gd = idx & 7;
    int gs  = gd ^ (row & 7);         // row&7 == global row&7 (half is 128-aligned)
    gl_lds16(baseH + row*64 + gs*8, lrfh + c*2048 + w*512);
    gl_lds16(baseL + row*64 + gs*8, lrfl + c*2048 + w*512);
  }
}

// ---------------- prep kernels ----------------
__global__ void split_kernel(const float* __restrict__ src, u16* __restrict__ hi,
                             u16* __restrict__ lo, int n4){
  int i = blockIdx.x*blockDim.x + threadIdx.x;
  if (i >= n4) return;
  float4 f = ((const float4*)src)[i];
  float ff[4] = {f.x,f.y,f.z,f.w};
  us4 hv, lv;
  #pragma unroll
  for (int j=0;j<4;j++){
    u16 h = f2bf(ff[j]);
    hv[j] = h;
    lv[j] = f2bf(ff[j] - bf2f(h));
  }
  ((us4*)hi)[i] = hv;
  if (lo) ((us4*)lo)[i] = lv;
}

// rf [H][HD][R] fp32 -> rf_t hi/lo [H][R][HD] bf16
__global__ void rf_split_kernel(const float* __restrict__ rf, u16* __restrict__ rhi,
                                u16* __restrict__ rlo){
  int idx = blockIdx.x*256 + threadIdx.x;     // over H*R*HD = 262144
  int d = idx & 63, r = (idx >> 6) & 255, h = idx >> 14;
  float f = rf[((size_t)h*HD_ + d)*R_ + r];
  u16 hh = f2bf(f);
  rhi[idx] = hh;
  rlo[idx] = f2bf(f - bf2f(hh));
}

// fused ||row||^2/2: lane (q,rr) holds 16 elems of row w*16+rr.
// result sql[r4] = 0.5*||row w*16+q*4+r4||^2 on every lane (matches C-layout rows).
__device__ __forceinline__ void rowsq(const float4& x0, const float4& x1,
                                      const float4& x2, const float4& x3,
                                      int q, float sql[4]){
  float s = x0.x*x0.x + x0.y*x0.y + x0.z*x0.z + x0.w*x0.w
          + x1.x*x1.x + x1.y*x1.y + x1.z*x1.z + x1.w*x1.w
          + x2.x*x2.x + x2.y*x2.y + x2.z*x2.z + x2.w*x2.w
          + x3.x*x3.x + x3.y*x3.y + x3.z*x3.z + x3.w*x3.w;
  s += __shfl_xor(s, 16);
  s += __shfl_xor(s, 32);
  #pragma unroll
  for (int r4=0;r4<4;r4++) sql[r4] = 0.5f * __shfl(s, q*4 + r4);
}

// ---------------- 128x128 MFMA GEMM, K=1024, A[M][K], B[N][K] (both bf16) ----------------
// Staging: global_load_lds width=16 (m97 pattern, 2-barrier K-loop).
// LDS chunk layout (1 KB per 16 rows x 32 k): lane l -> row c*16+(l>>2), pos p=l&3;
// pos p holds global 16B-group g = p ^ ((row>>1)&3)  (XOR swizzle -> free 2-way reads)
// NSPLIT==3: acc += Ah*Bh + Ah*Bl + Al*Bh   (split-bf16 ~fp32 precision)
// EPI 0: fp32 -> [b,h,s,hd]+bias | EPI 1: bf16 -> [b,h,hd,s]+bias | EPI 2: fp32 [m][n]+bias
template<int NSPLIT, int EPI>
__global__ __launch_bounds__(256, 2)
void gemm128(const u16* __restrict__ Ah, const u16* __restrict__ Al,
             const u16* __restrict__ Bh, const u16* __restrict__ Bl,
             const float* __restrict__ bias, float* __restrict__ outF,
             u16* __restrict__ outB){
  constexpr int NBUF = (NSPLIT==3) ? 4 : 2;
  __shared__ u16 lds[NBUF * 4096];
  const int tid = threadIdx.x, w = tid >> 6, lane = tid & 63;
  const int wm = w & 1, wn = w >> 1;
  const int m0 = blockIdx.x * 128, n0 = blockIdx.y * 128;
  const int q = lane >> 4, rr = lane & 15;

  const int c0 = w*2, c1 = w*2 + 1;
  const int row0 = c0*16 + (lane >> 2), row1 = c1*16 + (lane >> 2);
  const int g0 = (lane & 3) ^ ((row0 >> 1) & 3);
  const int g1 = (lane & 3) ^ ((row1 >> 1) & 3);
  const size_t a0 = (size_t)(m0 + row0)*1024 + g0*8;
  const size_t a1 = (size_t)(m0 + row1)*1024 + g1*8;
  const size_t b0 = (size_t)(n0 + row0)*1024 + g0*8;
  const size_t b1 = (size_t)(n0 + row1)*1024 + g1*8;

  f32x4 acc[4][4];
  #pragma unroll
  for (int i=0;i<4;i++)
    #pragma unroll
    for (int j=0;j<4;j++) acc[i][j] = f32x4{0.f,0.f,0.f,0.f};

  for (int kt=0; kt<32; kt++){
    const int k0 = kt*32;
    gl_lds16(Ah + a0 + k0, lds + 0*4096 + c0*512);
    gl_lds16(Ah + a1 + k0, lds + 0*4096 + c1*512);
    gl_lds16(Bh + b0 + k0, lds + 1*4096 + c0*512);
    gl_lds16(Bh + b1 + k0, lds + 1*4096 + c1*512);
    if constexpr (NSPLIT == 3){
      gl_lds16(Al + a0 + k0, lds + 2*4096 + c0*512);
      gl_lds16(Al + a1 + k0, lds + 2*4096 + c1*512);
      gl_lds16(Bl + b0 + k0, lds + 3*4096 + c0*512);
      gl_lds16(Bl + b1 + k0, lds + 3*4096 + c1*512);
    }
    __syncthreads();   // drains vmcnt -> staged data visible

    short8 afh[4], bfh[4], afl[4], bfl[4];
    #pragma unroll
    for (int i=0;i<4;i++){
      int r  = wm*64 + i*16 + rr;
      int o  = r*32 + ((q ^ ((r >> 1) & 3))*8);
      afh[i] = *(const short8*)(lds + 0*4096 + o);
      if constexpr (NSPLIT == 3) afl[i] = *(const short8*)(lds + 2*4096 + o);
      int rn = wn*64 + i*16 + rr;
      int on = rn*32 + ((q ^ ((rn >> 1) & 3))*8);
      bfh[i] = *(const short8*)(lds + 1*4096 + on);
      if constexpr (NSPLIT == 3) bfl[i] = *(const short8*)(lds + 3*4096 + on);
    }
    #pragma unroll
    for (int i=0;i<4;i++)
      #pragma unroll
      for (int j=0;j<4;j++){
        acc[i][j] = mfma16(afh[i], bfh[j], acc[i][j]);
        if constexpr (NSPLIT == 3){
          acc[i][j] = mfma16(afh[i], bfl[j], acc[i][j]);
          acc[i][j] = mfma16(afl[i], bfh[j], acc[i][j]);
        }
      }
    __syncthreads();   // protect LDS from next kt's DMA
  }

  #pragma unroll
  for (int i=0;i<4;i++){
    #pragma unroll
    for (int j=0;j<4;j++){
      int n  = n0 + wn*64 + j*16 + rr;
      float bb = bias[n];
      if constexpr (EPI == 1){
        int mb = m0 + wm*64 + i*16 + q*4;
        us4 pk;
        #pragma unroll
        for (int r4=0;r4<4;r4++) pk[r4] = f2bf(acc[i][j][r4] + bb);
        *(us4*)(outB + ((size_t)((mb >> 12)*H_ + (n >> 6))*HD_ + (n & 63))*S_ + (mb & 4095)) = pk;
      } else {
        #pragma unroll
        for (int r4=0;r4<4;r4++){
          int m = m0 + wm*64 + i*16 + q*4 + r4;
          float v = acc[i][j][r4] + bb;
          if constexpr (EPI == 0)
            outF[((size_t)((m >> 12)*H_ + (n >> 6)))*S_*HD_ + (size_t)(m & 4095)*HD_ + (n & 63)] = v;
          else
            outF[(size_t)m*1024 + n] = v;
        }
      }
    }
  }
}

// ---------------- fused k-feature + kv' split-K partial, R-SPLIT ----------------
// grid (SPLITK_, BH_, 2); block covers 512 s rows x HALF the R features (128 rows).
// blockIdx.z = th picks rf rows [th*128, th*128+128). kv rows are DISJOINT across
// th (kv'[r][d] sums over s only) -> both halves write disjoint rows of kvp16,
// kv_reduce unchanged. LDS = kp 18 KB + rf half 32 KB = 50 KB -> 2-3 blocks/CU
// (R6 was 102 KB -> 1 block -> 1 wave/SIMD, zero TLP — the feat-kernel limiter).
// Registers also halve (accp[8], acc2[2][5]) -> natural alloc fits multi-block.
__global__ __launch_bounds__(256, 1)
void kfeat_kv_kernel(const float* __restrict__ k32,
                     const u16* __restrict__ rfh, const u16* __restrict__ rfl,
                     const u16* __restrict__ vt, u16* __restrict__ kvp16){
  __shared__ u16 kp[128*72];
  __shared__ u16 lrfh[128*HD_];
  __shared__ u16 lrfl[128*HD_];
  const int sp = blockIdx.x, hb = blockIdx.y, th = blockIdx.z, h = hb & 15;
  const int tid = threadIdx.x, w = tid >> 6, lane = tid & 63;
  const int q = lane >> 4, rr = lane & 15;
  const int sw8 = rr & 7;

  stage_rf_half(rfh, rfl, h, th, tid, w, lrfh, lrfl);

  short8 ones;
  { u16 one = (rr == 0) ? (u16)0x3F80 : (u16)0;
    #pragma unroll
    for (int j=0;j<8;j++) ones[j] = (short)one; }

  f32x4 acc2[2][5];
  #pragma unroll
  for (int a=0;a<2;a++)
    #pragma unroll
    for (int t=0;t<5;t++) acc2[a][t] = f32x4{0.f,0.f,0.f,0.f};

  __syncthreads();   // rf staged (drains DMA)

  // preload sub 0's k rows
  const float* ap0 = k32 + ((size_t)hb*S_ + sp*(S_/SPLITK_) + w*16 + rr)*HD_ + q*8;
  float4 x0 = *(const float4*)(ap0);
  float4 x1 = *(const float4*)(ap0 + 4);
  float4 x2 = *(const float4*)(ap0 + 32);
  float4 x3 = *(const float4*)(ap0 + 36);

  for (int sub=0; sub<(S_/SPLITK_)/64; sub++){
    const int s0 = sp*(S_/SPLITK_) + sub*64;
    float sql[4];
    rowsq(x0, x1, x2, x3, q, sql);
    short8 ah[2], al[2];
    cvt8(x0, x1, ah[0], al[0]);
    cvt8(x2, x3, ah[1], al[1]);
    if (sub < (S_/SPLITK_)/64 - 1){   // prefetch next sub's k rows
      const float* apn = k32 + ((size_t)hb*S_ + s0 + 64 + w*16 + rr)*HD_ + q*8;
      x0 = *(const float4*)(apn);
      x1 = *(const float4*)(apn + 4);
      x2 = *(const float4*)(apn + 32);
      x3 = *(const float4*)(apn + 36);
    }

    f32x4 accp[8];
    #pragma unroll
    for (int tt=0;tt<8;tt++) accp[tt] = f32x4{0.f,0.f,0.f,0.f};
    #pragma unroll
    for (int tt=0;tt<8;tt++){
      const u16* lrow  = lrfh + (tt*16 + rr)*64;
      const u16* lrowl = lrfl + (tt*16 + rr)*64;
      short8 bh0 = *(const short8*)(lrow  + ((q     ^ sw8))*8);
      short8 bh1 = *(const short8*)(lrow  + (((q+4) ^ sw8))*8);
      short8 bl0 = *(const short8*)(lrowl + ((q     ^ sw8))*8);
      short8 bl1 = *(const short8*)(lrowl + (((q+4) ^ sw8))*8);
      f32x4 c = accp[tt];
      c = mfma16(ah[0], bh0, c); c = mfma16(ah[0], bl0, c); c = mfma16(al[0], bh0, c);
      c = mfma16(ah[1], bh1, c); c = mfma16(ah[1], bl1, c); c = mfma16(al[1], bh1, c);
      accp[tt] = c;
    }
    #pragma unroll
    for (int tt=0;tt<8;tt++){
      us4 pk;
      #pragma unroll
      for (int r4=0;r4<4;r4++) pk[r4] = f2bf(__expf(accp[tt][r4] - sql[r4]));
      *(us4*)(kp + (tt*16 + rr)*72 + w*16 + q*4) = pk;
    }
    __syncthreads();
    #pragma unroll
    for (int ks=0; ks<2; ks++){
      short8 af[2];
      #pragma unroll
      for (int a=0;a<2;a++)
        af[a] = *(const short8*)(kp + (w*32 + a*16 + rr)*72 + ks*32 + q*8);
      #pragma unroll
      for (int t=0;t<5;t++){
        short8 bf;
        if (t < 4)
          bf = *(const short8*)(vt + ((size_t)hb*HD_ + t*16 + rr)*S_ + s0 + ks*32 + q*8);
        else
          bf = ones;
        #pragma unroll
        for (int a=0;a<2;a++) acc2[a][t] = mfma16(af[a], bf, acc2[a][t]);
      }
    }
    __syncthreads();
  }
  u16* op = kvp16 + ((size_t)hb*SPLITK_ + sp)*R_*80;
  #pragma unroll
  for (int a=0;a<2;a++)
    #pragma unroll
    for (int t=0;t<5;t++)
      #pragma unroll
      for (int r4=0;r4<4;r4++){
        int r = th*128 + w*32 + a*16 + q*4 + r4;
        int c = t*16 + rr;
        op[r*80 + c] = f2bf(acc2[a][t][r4]);
      }
}

// reduce bf16 kv partials: kv_t[hb][d][r] bf16, ksum[hb][r] fp32
__global__ void kv_reduce_kernel(const u16* __restrict__ kvp16, u16* __restrict__ kvt,
                                 float* __restrict__ ksum){
  int r = blockIdx.x, hb = blockIdx.y, c = threadIdx.x;
  if (c >= 65) return;
  const u16* base = kvp16 + (size_t)hb*SPLITK_*R_*80 + r*80 + c;
  float s = 0.f;
  #pragma unroll
  for (int sp=0; sp<SPLITK_; sp++) s += bf2f(base[(size_t)sp*R_*80]);
  if (c < 64) kvt[((size_t)hb*HD_ + c)*R_ + r] = f2bf(s);
  else        ksum[(size_t)hb*R_ + r] = s;
}

// ---------------- fused q-feature + attn + norm (R6-exact, proven 650us config) ----
// grid (16, BH_); block covers 256 s rows, 4 sub-chunks of 64.
// rf_hi+rf_lo staged in LDS once per block (64 KB, XOR-swizzled source).
// qp wave-private -> no barriers in sub loop. LDS 33.8+64 = 99.3 KB -> 1 block/CU.
__global__ __launch_bounds__(256, 1)
void qfeat_attn_kernel(const float* __restrict__ q32,
                       const u16* __restrict__ rfh, const u16* __restrict__ rfl,
                       const u16* __restrict__ kvt, const float* __restrict__ ksum,
                       u16* __restrict__ attn_c){
  __shared__ u16 qp[64*264];
  __shared__ u16 lrfh[R_*HD_];
  __shared__ u16 lrfl[R_*HD_];
  const int sc4 = blockIdx.x, hb = blockIdx.y, h = hb & 15, b = hb >> 4;
  const int tid = threadIdx.x, w = tid >> 6, lane = tid & 63;
  const int q = lane >> 4, rr = lane & 15;
  const int sw8 = rr & 7;

  stage_rf_full(rfh, rfl, h, tid, w, lrfh, lrfl);

  float kslv[16];
  #pragma unroll
  for (int t=0;t<16;t++) kslv[t] = ksum[(size_t)hb*R_ + t*16 + rr];

  __syncthreads();   // rf staged (drains DMA)

  // preload sub 0's q rows
  const float* ap0 = q32 + ((size_t)hb*S_ + sc4*256 + w*16 + rr)*HD_ + q*8;
  float4 x0 = *(const float4*)(ap0);
  float4 x1 = *(const float4*)(ap0 + 4);
  float4 x2 = *(const float4*)(ap0 + 32);
  float4 x3 = *(const float4*)(ap0 + 36);

  for (int sub=0; sub<4; sub++){
    const int s0 = sc4*256 + sub*64;
    // ---- phase 1: q' for 64 s rows ----
    float sql[4];
    rowsq(x0, x1, x2, x3, q, sql);
    short8 ah[2], al[2];
    cvt8(x0, x1, ah[0], al[0]);
    cvt8(x2, x3, ah[1], al[1]);
    if (sub < 3){   // prefetch next sub's q rows (completes under phase 1+2)
      const float* apn = q32 + ((size_t)hb*S_ + s0 + 64 + w*16 + rr)*HD_ + q*8;
      x0 = *(const float4*)(apn);
      x1 = *(const float4*)(apn + 4);
      x2 = *(const float4*)(apn + 32);
      x3 = *(const float4*)(apn + 36);
    }

    f32x4 accp[16];
    #pragma unroll
    for (int t=0;t<16;t++) accp[t] = f32x4{0.f,0.f,0.f,0.f};
    #pragma unroll
    for (int t=0;t<16;t++){
      const u16* lrow  = lrfh + (t*16 + rr)*64;
      const u16* lrowl = lrfl + (t*16 + rr)*64;
      short8 bh0 = *(const short8*)(lrow  + ((q     ^ sw8))*8);
      short8 bh1 = *(const short8*)(lrow  + (((q+4) ^ sw8))*8);
      short8 bl0 = *(const short8*)(lrowl + ((q     ^ sw8))*8);
      short8 bl1 = *(const short8*)(lrowl + (((q+4) ^ sw8))*8);
      f32x4 c = accp[t];
      c = mfma16(ah[0], bh0, c); c = mfma16(ah[0], bl0, c); c = mfma16(al[0], bh0, c);
      c = mfma16(ah[1], bh1, c); c = mfma16(ah[1], bl1, c); c = mfma16(al[1], bh1, c);
      accp[t] = c;
    }
    // exp -> qp (A-layout staging) + in-register norm partials
    float npl[4] = {0.f, 0.f, 0.f, 0.f};
    #pragma unroll
    for (int t=0;t<16;t++){
      us4 pk;
      #pragma unroll
      for (int r4=0;r4<4;r4++){
        float e = __expf(accp[t][r4] - sql[r4]);
        npl[r4] += e * kslv[t];
        pk[r4] = f2bf(e);
      }
      #pragma unroll
      for (int r4=0;r4<4;r4++)
        qp[(w*16 + q*4 + r4)*264 + t*16 + rr] = pk[r4];
    }
    // reduce norm over rr (bits 0-3 of lane) -> lanes keep rows q*4+r4
    #pragma unroll
    for (int r4=0;r4<4;r4++){
      npl[r4] += __shfl_xor(npl[r4], 1);
      npl[r4] += __shfl_xor(npl[r4], 2);
      npl[r4] += __shfl_xor(npl[r4], 4);
      npl[r4] += __shfl_xor(npl[r4], 8);
    }
    // no barrier: qp rows read below are the ones this wave just wrote (in-order DS)

    // ---- phase 2: attn = q' @ kv'^T ; wave w owns s rows w*16..w*16+15 ----
    f32x4 acc[4];
    #pragma unroll
    for (int t=0;t<4;t++) acc[t] = f32x4{0.f,0.f,0.f,0.f};
    #pragma unroll
    for (int ks=0; ks<8; ks++){
      short8 af = *(const short8*)(qp + (w*16 + rr)*264 + ks*32 + q*8);
      #pragma unroll
      for (int t=0;t<4;t++){
        short8 bf = *(const short8*)(kvt + ((size_t)hb*HD_ + t*16 + rr)*R_ + ks*32 + q*8);
        acc[t] = mfma16(af, bf, acc[t]);
      }
    }

    #pragma unroll
    for (int t=0;t<4;t++)
      #pragma unroll
      for (int r4=0;r4<4;r4++){
        int sl = w*16 + q*4 + r4;
        int d  = t*16 + rr;
        float o = acc[t][r4] / (npl[r4] + 1e-6f);
        attn_c[((size_t)b*S_ + s0 + sl)*D_ + h*HD_ + d] = f2bf(o);
      }
    // no trailing barrier: next sub's qp writes are same-wave, in-order
  }
}

// ---------------- host ----------------
extern "C" void kernel_launch(void* const* d_in, const int* in_sizes, int n_in,
                              void* d_out, int out_size, void* d_ws, size_t ws_size,
                              hipStream_t stream){
  (void)in_sizes; (void)n_in; (void)out_size; (void)ws_size;
  const float* x  = (const float*)d_in[0];
  const float* wq = (const float*)d_in[1];
  const float* bq = (const float*)d_in[2];
  const float* wk = (const float*)d_in[3];
  const float* bk = (const float*)d_in[4];
  const float* wv = (const float*)d_in[5];
  const float* bv = (const float*)d_in[6];
  const float* wo = (const float*)d_in[7];
  const float* bo = (const float*)d_in[8];
  const float* rf = (const float*)d_in[9];
  float* out = (float*)d_out;

  char* p = (char*)d_ws;
  size_t off = 0;
  auto take = [&](size_t bytes)->char*{
    char* r = p + off; off += (bytes + 255) & ~(size_t)255; return r;
  };
  u16*  x_hi  = (u16*)take((size_t)M_*D_*2);
  u16*  x_lo  = (u16*)take((size_t)M_*D_*2);
  u16*  wq_hi = (u16*)take((size_t)D_*D_*2);
  u16*  wq_lo = (u16*)take((size_t)D_*D_*2);
  u16*  wk_hi = (u16*)take((size_t)D_*D_*2);
  u16*  wk_lo = (u16*)take((size_t)D_*D_*2);
  u16*  wv_hi = (u16*)take((size_t)D_*D_*2);
  u16*  wo_hi = (u16*)take((size_t)D_*D_*2);
  u16*  rf_hi = (u16*)take((size_t)H_*R_*HD_*2);
  u16*  rf_lo = (u16*)take((size_t)H_*R_*HD_*2);
  float* q32  = (float*)take((size_t)M_*D_*4);
  float* k32  = (float*)take((size_t)M_*D_*4);
  u16*  v_t   = (u16*)take((size_t)M_*D_*2);
  u16*  kvt   = (u16*)take((size_t)BH_*HD_*R_*2);
  float* ksum = (float*)take((size_t)BH_*R_*4);
  // aliases (stream-ordered reuse of dead buffers):
  u16* attn_c = x_hi;   // x_hi dead after V projection
  u16* kvp16  = x_lo;   // x_lo dead after K projection; 21 MB <= 33.5 MB

  // prep: splits
  split_kernel<<<dim3((M_*D_)/1024), 256, 0, stream>>>(x,  x_hi,  x_lo,  (M_*D_)/4);
  split_kernel<<<dim3((D_*D_)/1024), 256, 0, stream>>>(wq, wq_hi, wq_lo, (D_*D_)/4);
  split_kernel<<<dim3((D_*D_)/1024), 256, 0, stream>>>(wk, wk_hi, wk_lo, (D_*D_)/4);
  split_kernel<<<dim3((D_*D_)/1024), 256, 0, stream>>>(wv, wv_hi, nullptr, (D_*D_)/4);
  split_kernel<<<dim3((D_*D_)/1024), 256, 0, stream>>>(wo, wo_hi, nullptr, (D_*D_)/4);
  rf_split_kernel<<<dim3((H_*R_*HD_)/256), 256, 0, stream>>>(rf, rf_hi, rf_lo);

  // projections
  gemm128<3,0><<<dim3(M_/128, D_/128), 256, 0, stream>>>(x_hi, x_lo, wq_hi, wq_lo, bq, q32, nullptr);
  gemm128<3,0><<<dim3(M_/128, D_/128), 256, 0, stream>>>(x_hi, x_lo, wk_hi, wk_lo, bk, k32, nullptr);
  gemm128<1,1><<<dim3(M_/128, D_/128), 256, 0, stream>>>(x_hi, nullptr, wv_hi, nullptr, bv, nullptr, v_t);

  // k' -> kv partials (R-split across z) -> reduce
  kfeat_kv_kernel<<<dim3(SPLITK_, BH_, 2), 256, 0, stream>>>(k32, rf_hi, rf_lo, v_t, kvp16);
  kv_reduce_kernel<<<dim3(R_, BH_), 128, 0, stream>>>(kvp16, kvt, ksum);

  // q' -> attn -> attn_c
  qfeat_attn_kernel<<<dim3(16, BH_), 256, 0, stream>>>(q32, rf_hi, rf_lo, kvt, ksum, attn_c);

  // output projection
  gemm128<1,2><<<dim3(M_/128, D_/128), 256, 0, stream>>>(attn_c, nullptr, wo_hi, nullptr, bo, out, nullptr);
}

// Round 10
// 595.516 us; speedup vs baseline: 1.3346x; 1.0286x over previous
//
#include <hip/hip_runtime.h>
#include <stdint.h>

#define B_  4
#define S_  4096
#define D_  1024
#define H_  16
#define R_  256
#define HD_ 64
#define BH_ 64        // B_*H_
#define M_  16384     // B_*S_
#define SPLITK_ 8     // kv split-K partials, bf16: 8*64*256*80*2 = 21 MB <= x_lo (33.5 MB)

typedef uint16_t u16;
typedef __attribute__((ext_vector_type(8))) short short8;
typedef __attribute__((ext_vector_type(4))) float f32x4;
typedef __attribute__((ext_vector_type(4))) unsigned short us4;

__device__ __forceinline__ u16 f2bf(float f){
  union { float f; uint32_t u; } v; v.f = f;
  uint32_t r = v.u + 0x7FFFu + ((v.u >> 16) & 1u);
  return (u16)(r >> 16);
}
__device__ __forceinline__ float bf2f(u16 h){
  union { uint32_t u; float f; } v; v.u = ((uint32_t)h) << 16;
  return v.f;
}
__device__ __forceinline__ f32x4 mfma16(short8 a, short8 b, f32x4 c){
  return __builtin_amdgcn_mfma_f32_16x16x32_bf16(a, b, c, 0, 0, 0);
}
// async global->LDS DMA, 16B per lane; LDS dest = wave-uniform base + lane*16,
// global source address is PER-LANE (enables pre-swizzled staging, rule #21)
__device__ __forceinline__ void gl_lds16(const u16* g, u16* l){
  __builtin_amdgcn_global_load_lds((const __attribute__((address_space(1))) void*)g,
                                   (__attribute__((address_space(3))) void*)l, 16, 0, 0);
}
// split a float8 (two float4) into bf16 hi + lo fragments
__device__ __forceinline__ void cvt8(const float4& a, const float4& b, short8& hi, short8& lo){
  float f[8] = {a.x,a.y,a.z,a.w,b.x,b.y,b.z,b.w};
  #pragma unroll
  for (int j=0;j<8;j++){
    u16 h = f2bf(f[j]);
    hi[j] = (short)h;
    lo[j] = (short)f2bf(f[j] - bf2f(h));
  }
}

// Stage rf_hi/rf_lo (full 256 rows) for one head into LDS, bank-swizzle
// gs = gd ^ (row&7) applied on the GLOBAL source address (LDS dest stays linear,
// rule #21). Read side XORs the same way. 256-thread blocks.
__device__ __forceinline__ void stage_rf_full(const u16* __restrict__ rfh,
                                              const u16* __restrict__ rfl,
                                              int h, int tid, int w,
                                              u16* lrfh, u16* lrfl){
  const u16* baseH = rfh + (size_t)h*(R_*HD_);
  const u16* baseL = rfl + (size_t)h*(R_*HD_);
  #pragma unroll
  for (int c=0;c<8;c++){
    int idx = c*256 + tid;            // 0..2047 <-> (row 0..255, group 0..7)
    int row = idx >> 3, gd = idx & 7;
    int gs  = gd ^ (row & 7);         // inverse swizzle on source
    gl_lds16(baseH + row*64 + gs*8, lrfh + c*2048 + w*512);
    gl_lds16(baseL + row*64 + gs*8, lrfl + c*2048 + w*512);
  }
}

// Stage a 128-row HALF of rf_hi/rf_lo (rows [th*128, th*128+128)), same swizzle.
__device__ __forceinline__ void stage_rf_half(const u16* __restrict__ rfh,
                                              const u16* __restrict__ rfl,
                                              int h, int th, int tid, int w,
                                              u16* lrfh, u16* lrfl){
  const u16* baseH = rfh + (size_t)h*(R_*HD_) + (size_t)th*128*HD_;
  const u16* baseL = rfl + (size_t)h*(R_*HD_) + (size_t)th*128*HD_;
  #pragma unroll
  for (int c=0;c<4;c++){
    int idx = c*256 + tid;            // 0..1023 <-> (row 0..127, group 0..7)
    int row = idx >> 3, gd = idx & 7;
    int gs  = gd ^ (row & 7);         // row&7 == global row&7 (half is 128-aligned)
    gl_lds16(baseH + row*64 + gs*8, lrfh + c*2048 + w*512);
    gl_lds16(baseL + row*64 + gs*8, lrfl + c*2048 + w*512);
  }
}

// ---------------- prep kernels ----------------
__global__ void split_kernel(const float* __restrict__ src, u16* __restrict__ hi,
                             u16* __restrict__ lo, int n4){
  int i = blockIdx.x*blockDim.x + threadIdx.x;
  if (i >= n4) return;
  float4 f = ((const float4*)src)[i];
  float ff[4] = {f.x,f.y,f.z,f.w};
  us4 hv, lv;
  #pragma unroll
  for (int j=0;j<4;j++){
    u16 h = f2bf(ff[j]);
    hv[j] = h;
    lv[j] = f2bf(ff[j] - bf2f(h));
  }
  ((us4*)hi)[i] = hv;
  if (lo) ((us4*)lo)[i] = lv;
}

// rf [H][HD][R] fp32 -> rf_t hi/lo [H][R][HD] bf16
__global__ void rf_split_kernel(const float* __restrict__ rf, u16* __restrict__ rhi,
                                u16* __restrict__ rlo){
  int idx = blockIdx.x*256 + threadIdx.x;     // over H*R*HD = 262144
  int d = idx & 63, r = (idx >> 6) & 255, h = idx >> 14;
  float f = rf[((size_t)h*HD_ + d)*R_ + r];
  u16 hh = f2bf(f);
  rhi[idx] = hh;
  rlo[idx] = f2bf(f - bf2f(hh));
}

// fused ||row||^2/2: lane (q,rr) holds 16 elems of row w*16+rr.
// result sql[r4] = 0.5*||row w*16+q*4+r4||^2 on every lane (matches C-layout rows).
__device__ __forceinline__ void rowsq(const float4& x0, const float4& x1,
                                      const float4& x2, const float4& x3,
                                      int q, float sql[4]){
  float s = x0.x*x0.x + x0.y*x0.y + x0.z*x0.z + x0.w*x0.w
          + x1.x*x1.x + x1.y*x1.y + x1.z*x1.z + x1.w*x1.w
          + x2.x*x2.x + x2.y*x2.y + x2.z*x2.z + x2.w*x2.w
          + x3.x*x3.x + x3.y*x3.y + x3.z*x3.z + x3.w*x3.w;
  s += __shfl_xor(s, 16);
  s += __shfl_xor(s, 32);
  #pragma unroll
  for (int r4=0;r4<4;r4++) sql[r4] = 0.5f * __shfl(s, q*4 + r4);
}

// ---------------- 128x128 MFMA GEMM, K=1024, A[M][K], B[N][K] (both bf16) ----------------
// Staging: global_load_lds width=16 (m97 pattern, 2-barrier K-loop).
// LDS chunk layout (1 KB per 16 rows x 32 k): lane l -> row c*16+(l>>2), pos p=l&3;
// pos p holds global 16B-group g = p ^ ((row>>1)&3)  (XOR swizzle -> free 2-way reads)
// NSPLIT==3: acc += Ah*Bh + Ah*Bl + Al*Bh   (split-bf16 ~fp32 precision)
// EPI 0: fp32 -> [b,h,s,hd]+bias | EPI 1: bf16 -> [b,h,hd,s]+bias | EPI 2: fp32 [m][n]+bias
template<int NSPLIT, int EPI>
__global__ __launch_bounds__(256, 2)
void gemm128(const u16* __restrict__ Ah, const u16* __restrict__ Al,
             const u16* __restrict__ Bh, const u16* __restrict__ Bl,
             const float* __restrict__ bias, float* __restrict__ outF,
             u16* __restrict__ outB){
  constexpr int NBUF = (NSPLIT==3) ? 4 : 2;
  __shared__ u16 lds[NBUF * 4096];
  const int tid = threadIdx.x, w = tid >> 6, lane = tid & 63;
  const int wm = w & 1, wn = w >> 1;
  const int m0 = blockIdx.x * 128, n0 = blockIdx.y * 128;
  const int q = lane >> 4, rr = lane & 15;

  const int c0 = w*2, c1 = w*2 + 1;
  const int row0 = c0*16 + (lane >> 2), row1 = c1*16 + (lane >> 2);
  const int g0 = (lane & 3) ^ ((row0 >> 1) & 3);
  const int g1 = (lane & 3) ^ ((row1 >> 1) & 3);
  const size_t a0 = (size_t)(m0 + row0)*1024 + g0*8;
  const size_t a1 = (size_t)(m0 + row1)*1024 + g1*8;
  const size_t b0 = (size_t)(n0 + row0)*1024 + g0*8;
  const size_t b1 = (size_t)(n0 + row1)*1024 + g1*8;

  f32x4 acc[4][4];
  #pragma unroll
  for (int i=0;i<4;i++)
    #pragma unroll
    for (int j=0;j<4;j++) acc[i][j] = f32x4{0.f,0.f,0.f,0.f};

  for (int kt=0; kt<32; kt++){
    const int k0 = kt*32;
    gl_lds16(Ah + a0 + k0, lds + 0*4096 + c0*512);
    gl_lds16(Ah + a1 + k0, lds + 0*4096 + c1*512);
    gl_lds16(Bh + b0 + k0, lds + 1*4096 + c0*512);
    gl_lds16(Bh + b1 + k0, lds + 1*4096 + c1*512);
    if constexpr (NSPLIT == 3){
      gl_lds16(Al + a0 + k0, lds + 2*4096 + c0*512);
      gl_lds16(Al + a1 + k0, lds + 2*4096 + c1*512);
      gl_lds16(Bl + b0 + k0, lds + 3*4096 + c0*512);
      gl_lds16(Bl + b1 + k0, lds + 3*4096 + c1*512);
    }
    __syncthreads();   // drains vmcnt -> staged data visible

    short8 afh[4], bfh[4], afl[4], bfl[4];
    #pragma unroll
    for (int i=0;i<4;i++){
      int r  = wm*64 + i*16 + rr;
      int o  = r*32 + ((q ^ ((r >> 1) & 3))*8);
      afh[i] = *(const short8*)(lds + 0*4096 + o);
      if constexpr (NSPLIT == 3) afl[i] = *(const short8*)(lds + 2*4096 + o);
      int rn = wn*64 + i*16 + rr;
      int on = rn*32 + ((q ^ ((rn >> 1) & 3))*8);
      bfh[i] = *(const short8*)(lds + 1*4096 + on);
      if constexpr (NSPLIT == 3) bfl[i] = *(const short8*)(lds + 3*4096 + on);
    }
    #pragma unroll
    for (int i=0;i<4;i++)
      #pragma unroll
      for (int j=0;j<4;j++){
        acc[i][j] = mfma16(afh[i], bfh[j], acc[i][j]);
        if constexpr (NSPLIT == 3){
          acc[i][j] = mfma16(afh[i], bfl[j], acc[i][j]);
          acc[i][j] = mfma16(afl[i], bfh[j], acc[i][j]);
        }
      }
    __syncthreads();   // protect LDS from next kt's DMA
  }

  #pragma unroll
  for (int i=0;i<4;i++){
    #pragma unroll
    for (int j=0;j<4;j++){
      int n  = n0 + wn*64 + j*16 + rr;
      float bb = bias[n];
      if constexpr (EPI == 1){
        int mb = m0 + wm*64 + i*16 + q*4;
        us4 pk;
        #pragma unroll
        for (int r4=0;r4<4;r4++) pk[r4] = f2bf(acc[i][j][r4] + bb);
        *(us4*)(outB + ((size_t)((mb >> 12)*H_ + (n >> 6))*HD_ + (n & 63))*S_ + (mb & 4095)) = pk;
      } else {
        #pragma unroll
        for (int r4=0;r4<4;r4++){
          int m = m0 + wm*64 + i*16 + q*4 + r4;
          float v = acc[i][j][r4] + bb;
          if constexpr (EPI == 0)
            outF[((size_t)((m >> 12)*H_ + (n >> 6)))*S_*HD_ + (size_t)(m & 4095)*HD_ + (n & 63)] = v;
          else
            outF[(size_t)m*1024 + n] = v;
        }
      }
    }
  }
}

// ---------------- fused k-feature + kv' split-K partial, R-SPLIT (R9-exact) --------
// grid (SPLITK_, BH_, 2); block covers 512 s rows x HALF the R features (128 rows).
// kv rows DISJOINT across th -> both halves write disjoint rows of kvp16.
// LDS = kp 18 KB + rf half 32 KB = 50 KB -> multi-block/CU TLP (the R9 win).
__global__ __launch_bounds__(256, 1)
void kfeat_kv_kernel(const float* __restrict__ k32,
                     const u16* __restrict__ rfh, const u16* __restrict__ rfl,
                     const u16* __restrict__ vt, u16* __restrict__ kvp16){
  __shared__ u16 kp[128*72];
  __shared__ u16 lrfh[128*HD_];
  __shared__ u16 lrfl[128*HD_];
  const int sp = blockIdx.x, hb = blockIdx.y, th = blockIdx.z, h = hb & 15;
  const int tid = threadIdx.x, w = tid >> 6, lane = tid & 63;
  const int q = lane >> 4, rr = lane & 15;
  const int sw8 = rr & 7;

  stage_rf_half(rfh, rfl, h, th, tid, w, lrfh, lrfl);

  short8 ones;
  { u16 one = (rr == 0) ? (u16)0x3F80 : (u16)0;
    #pragma unroll
    for (int j=0;j<8;j++) ones[j] = (short)one; }

  f32x4 acc2[2][5];
  #pragma unroll
  for (int a=0;a<2;a++)
    #pragma unroll
    for (int t=0;t<5;t++) acc2[a][t] = f32x4{0.f,0.f,0.f,0.f};

  __syncthreads();   // rf staged (drains DMA)

  // preload sub 0's k rows
  const float* ap0 = k32 + ((size_t)hb*S_ + sp*(S_/SPLITK_) + w*16 + rr)*HD_ + q*8;
  float4 x0 = *(const float4*)(ap0);
  float4 x1 = *(const float4*)(ap0 + 4);
  float4 x2 = *(const float4*)(ap0 + 32);
  float4 x3 = *(const float4*)(ap0 + 36);

  for (int sub=0; sub<(S_/SPLITK_)/64; sub++){
    const int s0 = sp*(S_/SPLITK_) + sub*64;
    float sql[4];
    rowsq(x0, x1, x2, x3, q, sql);
    short8 ah[2], al[2];
    cvt8(x0, x1, ah[0], al[0]);
    cvt8(x2, x3, ah[1], al[1]);
    if (sub < (S_/SPLITK_)/64 - 1){   // prefetch next sub's k rows
      const float* apn = k32 + ((size_t)hb*S_ + s0 + 64 + w*16 + rr)*HD_ + q*8;
      x0 = *(const float4*)(apn);
      x1 = *(const float4*)(apn + 4);
      x2 = *(const float4*)(apn + 32);
      x3 = *(const float4*)(apn + 36);
    }

    f32x4 accp[8];
    #pragma unroll
    for (int tt=0;tt<8;tt++) accp[tt] = f32x4{0.f,0.f,0.f,0.f};
    #pragma unroll
    for (int tt=0;tt<8;tt++){
      const u16* lrow  = lrfh + (tt*16 + rr)*64;
      const u16* lrowl = lrfl + (tt*16 + rr)*64;
      short8 bh0 = *(const short8*)(lrow  + ((q     ^ sw8))*8);
      short8 bh1 = *(const short8*)(lrow  + (((q+4) ^ sw8))*8);
      short8 bl0 = *(const short8*)(lrowl + ((q     ^ sw8))*8);
      short8 bl1 = *(const short8*)(lrowl + (((q+4) ^ sw8))*8);
      f32x4 c = accp[tt];
      c = mfma16(ah[0], bh0, c); c = mfma16(ah[0], bl0, c); c = mfma16(al[0], bh0, c);
      c = mfma16(ah[1], bh1, c); c = mfma16(ah[1], bl1, c); c = mfma16(al[1], bh1, c);
      accp[tt] = c;
    }
    #pragma unroll
    for (int tt=0;tt<8;tt++){
      us4 pk;
      #pragma unroll
      for (int r4=0;r4<4;r4++) pk[r4] = f2bf(__expf(accp[tt][r4] - sql[r4]));
      *(us4*)(kp + (tt*16 + rr)*72 + w*16 + q*4) = pk;
    }
    __syncthreads();
    #pragma unroll
    for (int ks=0; ks<2; ks++){
      short8 af[2];
      #pragma unroll
      for (int a=0;a<2;a++)
        af[a] = *(const short8*)(kp + (w*32 + a*16 + rr)*72 + ks*32 + q*8);
      #pragma unroll
      for (int t=0;t<5;t++){
        short8 bf;
        if (t < 4)
          bf = *(const short8*)(vt + ((size_t)hb*HD_ + t*16 + rr)*S_ + s0 + ks*32 + q*8);
        else
          bf = ones;
        #pragma unroll
        for (int a=0;a<2;a++) acc2[a][t] = mfma16(af[a], bf, acc2[a][t]);
      }
    }
    __syncthreads();
  }
  u16* op = kvp16 + ((size_t)hb*SPLITK_ + sp)*R_*80;
  #pragma unroll
  for (int a=0;a<2;a++)
    #pragma unroll
    for (int t=0;t<5;t++)
      #pragma unroll
      for (int r4=0;r4<4;r4++){
        int r = th*128 + w*32 + a*16 + q*4 + r4;
        int c = t*16 + rr;
        op[r*80 + c] = f2bf(acc2[a][t][r4]);
      }
}

// reduce bf16 kv partials: kv_t[hb][d][r] bf16, ksum[hb][r] fp32
__global__ void kv_reduce_kernel(const u16* __restrict__ kvp16, u16* __restrict__ kvt,
                                 float* __restrict__ ksum){
  int r = blockIdx.x, hb = blockIdx.y, c = threadIdx.x;
  if (c >= 65) return;
  const u16* base = kvp16 + (size_t)hb*SPLITK_*R_*80 + r*80 + c;
  float s = 0.f;
  #pragma unroll
  for (int sp=0; sp<SPLITK_; sp++) s += bf2f(base[(size_t)sp*R_*80]);
  if (c < 64) kvt[((size_t)hb*HD_ + c)*R_ + r] = f2bf(s);
  else        ksum[(size_t)hb*R_ + r] = s;
}

// ---------------- fused q-feature + attn + norm ----------------
// grid (8, BH_); block covers 512 s rows, 8 sub-chunks of 64.
// NEW vs R9: kvt[hb] (32 KB) staged in LDS with the same XOR-swizzled-source pattern
// as rf (kvt row stride 512 B puts all 16 rr-lanes of a phase-2 ds_read in one bank
// without it). Phase-2's 32 L2 loads/sub (latency-exposed at 1 wave/SIMD, re-read
// every sub AND every block) become ~60-cy LDS reads. Grid halved (16->8 in x, 8 subs)
// so the bigger stage amortizes 2x. LDS 33.8+64+32 = 129.8 KB -> still 1 block/CU
// (no occupancy change - pure latency reduction; allocator untouched: bounds(256,1)).
__global__ __launch_bounds__(256, 1)
void qfeat_attn_kernel(const float* __restrict__ q32,
                       const u16* __restrict__ rfh, const u16* __restrict__ rfl,
                       const u16* __restrict__ kvt, const float* __restrict__ ksum,
                       u16* __restrict__ attn_c){
  __shared__ u16 qp[64*264];
  __shared__ u16 lrfh[R_*HD_];
  __shared__ u16 lrfl[R_*HD_];
  __shared__ u16 lkvt[HD_*R_];      // 64 d-rows x 256 r, 32 KB
  const int sc8 = blockIdx.x, hb = blockIdx.y, h = hb & 15, b = hb >> 4;
  const int tid = threadIdx.x, w = tid >> 6, lane = tid & 63;
  const int q = lane >> 4, rr = lane & 15;
  const int sw8 = rr & 7;

  stage_rf_full(rfh, rfl, h, tid, w, lrfh, lrfl);
  // stage kvt[hb] (64 rows x 256 u16 = 512B rows, 32 groups of 16B each):
  // slot gd holds global group gd ^ (row&7); read side XORs identically.
  {
    const u16* kg = kvt + (size_t)hb*HD_*R_;
    #pragma unroll
    for (int c=0;c<8;c++){
      int idx = c*256 + tid;          // 0..2047 <-> (row 0..63, group 0..31)
      int row = idx >> 5, gd = idx & 31;
      int gs  = gd ^ (row & 7);
      gl_lds16(kg + row*256 + gs*8, lkvt + c*2048 + w*512);
    }
  }

  float kslv[16];
  #pragma unroll
  for (int t=0;t<16;t++) kslv[t] = ksum[(size_t)hb*R_ + t*16 + rr];

  __syncthreads();   // rf + kvt staged (drains DMA)

  // preload sub 0's q rows
  const float* ap0 = q32 + ((size_t)hb*S_ + sc8*512 + w*16 + rr)*HD_ + q*8;
  float4 x0 = *(const float4*)(ap0);
  float4 x1 = *(const float4*)(ap0 + 4);
  float4 x2 = *(const float4*)(ap0 + 32);
  float4 x3 = *(const float4*)(ap0 + 36);

  for (int sub=0; sub<8; sub++){
    const int s0 = sc8*512 + sub*64;
    // ---- phase 1: q' for 64 s rows ----
    float sql[4];
    rowsq(x0, x1, x2, x3, q, sql);
    short8 ah[2], al[2];
    cvt8(x0, x1, ah[0], al[0]);
    cvt8(x2, x3, ah[1], al[1]);
    if (sub < 7){   // prefetch next sub's q rows (completes under phase 1+2)
      const float* apn = q32 + ((size_t)hb*S_ + s0 + 64 + w*16 + rr)*HD_ + q*8;
      x0 = *(const float4*)(apn);
      x1 = *(const float4*)(apn + 4);
      x2 = *(const float4*)(apn + 32);
      x3 = *(const float4*)(apn + 36);
    }

    f32x4 accp[16];
    #pragma unroll
    for (int t=0;t<16;t++) accp[t] = f32x4{0.f,0.f,0.f,0.f};
    #pragma unroll
    for (int t=0;t<16;t++){
      const u16* lrow  = lrfh + (t*16 + rr)*64;
      const u16* lrowl = lrfl + (t*16 + rr)*64;
      short8 bh0 = *(const short8*)(lrow  + ((q     ^ sw8))*8);
      short8 bh1 = *(const short8*)(lrow  + (((q+4) ^ sw8))*8);
      short8 bl0 = *(const short8*)(lrowl + ((q     ^ sw8))*8);
      short8 bl1 = *(const short8*)(lrowl + (((q+4) ^ sw8))*8);
      f32x4 c = accp[t];
      c = mfma16(ah[0], bh0, c); c = mfma16(ah[0], bl0, c); c = mfma16(al[0], bh0, c);
      c = mfma16(ah[1], bh1, c); c = mfma16(ah[1], bl1, c); c = mfma16(al[1], bh1, c);
      accp[t] = c;
    }
    // exp -> qp (A-layout staging) + in-register norm partials
    float npl[4] = {0.f, 0.f, 0.f, 0.f};
    #pragma unroll
    for (int t=0;t<16;t++){
      us4 pk;
      #pragma unroll
      for (int r4=0;r4<4;r4++){
        float e = __expf(accp[t][r4] - sql[r4]);
        npl[r4] += e * kslv[t];
        pk[r4] = f2bf(e);
      }
      #pragma unroll
      for (int r4=0;r4<4;r4++)
        qp[(w*16 + q*4 + r4)*264 + t*16 + rr] = pk[r4];
    }
    // reduce norm over rr (bits 0-3 of lane) -> lanes keep rows q*4+r4
    #pragma unroll
    for (int r4=0;r4<4;r4++){
      npl[r4] += __shfl_xor(npl[r4], 1);
      npl[r4] += __shfl_xor(npl[r4], 2);
      npl[r4] += __shfl_xor(npl[r4], 4);
      npl[r4] += __shfl_xor(npl[r4], 8);
    }
    // no barrier: qp rows read below are the ones this wave just wrote (in-order DS)

    // ---- phase 2: attn = q' @ kv'^T ; wave w owns s rows w*16..w*16+15 ----
    f32x4 acc[4];
    #pragma unroll
    for (int t=0;t<4;t++) acc[t] = f32x4{0.f,0.f,0.f,0.f};
    #pragma unroll
    for (int ks=0; ks<8; ks++){
      short8 af = *(const short8*)(qp + (w*16 + rr)*264 + ks*32 + q*8);
      #pragma unroll
      for (int t=0;t<4;t++){
        short8 bf = *(const short8*)(lkvt + (t*16 + rr)*256 + (((ks*4 + q) ^ sw8))*8);
        acc[t] = mfma16(af, bf, acc[t]);
      }
    }

    #pragma unroll
    for (int t=0;t<4;t++)
      #pragma unroll
      for (int r4=0;r4<4;r4++){
        int sl = w*16 + q*4 + r4;
        int d  = t*16 + rr;
        float o = acc[t][r4] / (npl[r4] + 1e-6f);
        attn_c[((size_t)b*S_ + s0 + sl)*D_ + h*HD_ + d] = f2bf(o);
      }
    // no trailing barrier: next sub's qp writes are same-wave, in-order
  }
}

// ---------------- host ----------------
extern "C" void kernel_launch(void* const* d_in, const int* in_sizes, int n_in,
                              void* d_out, int out_size, void* d_ws, size_t ws_size,
                              hipStream_t stream){
  (void)in_sizes; (void)n_in; (void)out_size; (void)ws_size;
  const float* x  = (const float*)d_in[0];
  const float* wq = (const float*)d_in[1];
  const float* bq = (const float*)d_in[2];
  const float* wk = (const float*)d_in[3];
  const float* bk = (const float*)d_in[4];
  const float* wv = (const float*)d_in[5];
  const float* bv = (const float*)d_in[6];
  const float* wo = (const float*)d_in[7];
  const float* bo = (const float*)d_in[8];
  const float* rf = (const float*)d_in[9];
  float* out = (float*)d_out;

  char* p = (char*)d_ws;
  size_t off = 0;
  auto take = [&](size_t bytes)->char*{
    char* r = p + off; off += (bytes + 255) & ~(size_t)255; return r;
  };
  u16*  x_hi  = (u16*)take((size_t)M_*D_*2);
  u16*  x_lo  = (u16*)take((size_t)M_*D_*2);
  u16*  wq_hi = (u16*)take((size_t)D_*D_*2);
  u16*  wq_lo = (u16*)take((size_t)D_*D_*2);
  u16*  wk_hi = (u16*)take((size_t)D_*D_*2);
  u16*  wk_lo = (u16*)take((size_t)D_*D_*2);
  u16*  wv_hi = (u16*)take((size_t)D_*D_*2);
  u16*  wo_hi = (u16*)take((size_t)D_*D_*2);
  u16*  rf_hi = (u16*)take((size_t)H_*R_*HD_*2);
  u16*  rf_lo = (u16*)take((size_t)H_*R_*HD_*2);
  float* q32  = (float*)take((size_t)M_*D_*4);
  float* k32  = (float*)take((size_t)M_*D_*4);
  u16*  v_t   = (u16*)take((size_t)M_*D_*2);
  u16*  kvt   = (u16*)take((size_t)BH_*HD_*R_*2);
  float* ksum = (float*)take((size_t)BH_*R_*4);
  // aliases (stream-ordered reuse of dead buffers):
  u16* attn_c = x_hi;   // x_hi dead after V projection
  u16* kvp16  = x_lo;   // x_lo dead after K projection; 21 MB <= 33.5 MB

  // prep: splits
  split_kernel<<<dim3((M_*D_)/1024), 256, 0, stream>>>(x,  x_hi,  x_lo,  (M_*D_)/4);
  split_kernel<<<dim3((D_*D_)/1024), 256, 0, stream>>>(wq, wq_hi, wq_lo, (D_*D_)/4);
  split_kernel<<<dim3((D_*D_)/1024), 256, 0, stream>>>(wk, wk_hi, wk_lo, (D_*D_)/4);
  split_kernel<<<dim3((D_*D_)/1024), 256, 0, stream>>>(wv, wv_hi, nullptr, (D_*D_)/4);
  split_kernel<<<dim3((D_*D_)/1024), 256, 0, stream>>>(wo, wo_hi, nullptr, (D_*D_)/4);
  rf_split_kernel<<<dim3((H_*R_*HD_)/256), 256, 0, stream>>>(rf, rf_hi, rf_lo);

  // projections
  gemm128<3,0><<<dim3(M_/128, D_/128), 256, 0, stream>>>(x_hi, x_lo, wq_hi, wq_lo, bq, q32, nullptr);
  gemm128<3,0><<<dim3(M_/128, D_/128), 256, 0, stream>>>(x_hi, x_lo, wk_hi, wk_lo, bk, k32, nullptr);
  gemm128<1,1><<<dim3(M_/128, D_/128), 256, 0, stream>>>(x_hi, nullptr, wv_hi, nullptr, bv, nullptr, v_t);

  // k' -> kv partials (R-split across z) -> reduce
  kfeat_kv_kernel<<<dim3(SPLITK_, BH_, 2), 256, 0, stream>>>(k32, rf_hi, rf_lo, v_t, kvp16);
  kv_reduce_kernel<<<dim3(R_, BH_), 128, 0, stream>>>(kvp16, kvt, ksum);

  // q' -> attn -> attn_c
  qfeat_attn_kernel<<<dim3(8, BH_), 256, 0, stream>>>(q32, rf_hi, rf_lo, kvt, ksum, attn_c);

  // output projection
  gemm128<1,2><<<dim3(M_/128, D_/128), 256, 0, stream>>>(attn_c, nullptr, wo_hi, nullptr, bo, out, nullptr);
}

// Round 11
// 589.084 us; speedup vs baseline: 1.3492x; 1.0109x over previous
//
#include <hip/hip_runtime.h>
#include <stdint.h>

#define B_  4
#define S_  4096
#define D_  1024
#define H_  16
#define R_  256
#define HD_ 64
#define BH_ 64        // B_*H_
#define M_  16384     // B_*S_
#define SPLITK_ 8     // kv split-K partials, bf16: 8*64*256*80*2 = 21 MB <= x_lo (33.5 MB)

typedef uint16_t u16;
typedef __attribute__((ext_vector_type(8))) short short8;
typedef __attribute__((ext_vector_type(4))) float f32x4;
typedef __attribute__((ext_vector_type(4))) unsigned short us4;

__device__ __forceinline__ u16 f2bf(float f){
  union { float f; uint32_t u; } v; v.f = f;
  uint32_t r = v.u + 0x7FFFu + ((v.u >> 16) & 1u);
  return (u16)(r >> 16);
}
__device__ __forceinline__ float bf2f(u16 h){
  union { uint32_t u; float f; } v; v.u = ((uint32_t)h) << 16;
  return v.f;
}
__device__ __forceinline__ f32x4 mfma16(short8 a, short8 b, f32x4 c){
  return __builtin_amdgcn_mfma_f32_16x16x32_bf16(a, b, c, 0, 0, 0);
}
// async global->LDS DMA, 16B per lane; LDS dest = wave-uniform base + lane*16,
// global source address is PER-LANE (enables pre-swizzled staging, rule #21)
__device__ __forceinline__ void gl_lds16(const u16* g, u16* l){
  __builtin_amdgcn_global_load_lds((const __attribute__((address_space(1))) void*)g,
                                   (__attribute__((address_space(3))) void*)l, 16, 0, 0);
}
// split a float8 (two float4) into bf16 hi + lo fragments
__device__ __forceinline__ void cvt8(const float4& a, const float4& b, short8& hi, short8& lo){
  float f[8] = {a.x,a.y,a.z,a.w,b.x,b.y,b.z,b.w};
  #pragma unroll
  for (int j=0;j<8;j++){
    u16 h = f2bf(f[j]);
    hi[j] = (short)h;
    lo[j] = (short)f2bf(f[j] - bf2f(h));
  }
}

// Stage rf_hi/rf_lo (full 256 rows) for one head into LDS, bank-swizzle
// gs = gd ^ (row&7) applied on the GLOBAL source address (LDS dest stays linear,
// rule #21). Read side XORs the same way. 256-thread blocks.
__device__ __forceinline__ void stage_rf_full(const u16* __restrict__ rfh,
                                              const u16* __restrict__ rfl,
                                              int h, int tid, int w,
                                              u16* lrfh, u16* lrfl){
  const u16* baseH = rfh + (size_t)h*(R_*HD_);
  const u16* baseL = rfl + (size_t)h*(R_*HD_);
  #pragma unroll
  for (int c=0;c<8;c++){
    int idx = c*256 + tid;            // 0..2047 <-> (row 0..255, group 0..7)
    int row = idx >> 3, gd = idx & 7;
    int gs  = gd ^ (row & 7);         // inverse swizzle on source
    gl_lds16(baseH + row*64 + gs*8, lrfh + c*2048 + w*512);
    gl_lds16(baseL + row*64 + gs*8, lrfl + c*2048 + w*512);
  }
}

// Stage a 128-row HALF of rf_hi/rf_lo (rows [th*128, th*128+128)), same swizzle.
__device__ __forceinline__ void stage_rf_half(const u16* __restrict__ rfh,
                                              const u16* __restrict__ rfl,
                                              int h, int th, int tid, int w,
                                              u16* lrfh, u16* lrfl){
  const u16* baseH = rfh + (size_t)h*(R_*HD_) + (size_t)th*128*HD_;
  const u16* baseL = rfl + (size_t)h*(R_*HD_) + (size_t)th*128*HD_;
  #pragma unroll
  for (int c=0;c<4;c++){
    int idx = c*256 + tid;            // 0..1023 <-> (row 0..127, group 0..7)
    int row = idx >> 3, gd = idx & 7;
    int gs  = gd ^ (row & 7);         // row&7 == global row&7 (half is 128-aligned)
    gl_lds16(baseH + row*64 + gs*8, lrfh + c*2048 + w*512);
    gl_lds16(baseL + row*64 + gs*8, lrfl + c*2048 + w*512);
  }
}

// ---------------- merged prep kernel ----------------
// One launch handles: x split, wq/wk splits (into concatenated wqk), wv/wo hi-only
// splits, rf transpose-split, and the [bq|bk] bias concat. Region dispatch on
// blockIdx.x (block-uniform branch). Saves 5 launch gaps vs separate kernels.
#define XB_ ((M_*D_)/1024)   // 16384 blocks
#define WB_ ((D_*D_)/1024)   // 1024 blocks per weight
__device__ __forceinline__ void split_body(const float* __restrict__ src,
                                           u16* __restrict__ hi, u16* __restrict__ lo,
                                           int bid, int tid){
  int i = bid*256 + tid;   // float4 index (regions are exact multiples of 256)
  float4 f = ((const float4*)src)[i];
  float ff[4] = {f.x,f.y,f.z,f.w};
  us4 hv, lv;
  #pragma unroll
  for (int j=0;j<4;j++){
    u16 h = f2bf(ff[j]);
    hv[j] = h;
    lv[j] = f2bf(ff[j] - bf2f(h));
  }
  ((us4*)hi)[i] = hv;
  if (lo) ((us4*)lo)[i] = lv;
}
__global__ void prep_kernel(const float* __restrict__ x,  const float* __restrict__ wq,
                            const float* __restrict__ wk, const float* __restrict__ wv,
                            const float* __restrict__ wo, const float* __restrict__ rf,
                            const float* __restrict__ bq, const float* __restrict__ bk,
                            u16* __restrict__ x_hi, u16* __restrict__ x_lo,
                            u16* __restrict__ wqk_hi, u16* __restrict__ wqk_lo,
                            u16* __restrict__ wv_hi, u16* __restrict__ wo_hi,
                            u16* __restrict__ rf_hi, u16* __restrict__ rf_lo,
                            float* __restrict__ bqk){
  int bid = blockIdx.x, tid = threadIdx.x;
  if (bid < XB_){ split_body(x, x_hi, x_lo, bid, tid); return; }
  bid -= XB_;
  if (bid < WB_){ split_body(wq, wqk_hi, wqk_lo, bid, tid); return; }
  bid -= WB_;
  if (bid < WB_){ split_body(wk, wqk_hi + (size_t)D_*D_, wqk_lo + (size_t)D_*D_, bid, tid); return; }
  bid -= WB_;
  if (bid < WB_){ split_body(wv, wv_hi, nullptr, bid, tid); return; }
  bid -= WB_;
  if (bid < WB_){ split_body(wo, wo_hi, nullptr, bid, tid); return; }
  bid -= WB_;
  if (bid < 1024){
    // rf [H][HD][R] fp32 -> rf_t hi/lo [H][R][HD] bf16
    int idx = bid*256 + tid;          // over H*R*HD = 262144
    int d = idx & 63, r = (idx >> 6) & 255, h = idx >> 14;
    float f = rf[((size_t)h*HD_ + d)*R_ + r];
    u16 hh = f2bf(f);
    rf_hi[idx] = hh;
    rf_lo[idx] = f2bf(f - bf2f(hh));
    return;
  }
  bid -= 1024;
  int i = bid*256 + tid;              // bias concat, 2048 floats (8 blocks)
  if (i < 1024)       bqk[i] = bq[i];
  else if (i < 2048)  bqk[i] = bk[i - 1024];
}

// fused ||row||^2/2: lane (q,rr) holds 16 elems of row w*16+rr.
// result sql[r4] = 0.5*||row w*16+q*4+r4||^2 on every lane (matches C-layout rows).
__device__ __forceinline__ void rowsq(const float4& x0, const float4& x1,
                                      const float4& x2, const float4& x3,
                                      int q, float sql[4]){
  float s = x0.x*x0.x + x0.y*x0.y + x0.z*x0.z + x0.w*x0.w
          + x1.x*x1.x + x1.y*x1.y + x1.z*x1.z + x1.w*x1.w
          + x2.x*x2.x + x2.y*x2.y + x2.z*x2.z + x2.w*x2.w
          + x3.x*x3.x + x3.y*x3.y + x3.z*x3.z + x3.w*x3.w;
  s += __shfl_xor(s, 16);
  s += __shfl_xor(s, 32);
  #pragma unroll
  for (int r4=0;r4<4;r4++) sql[r4] = 0.5f * __shfl(s, q*4 + r4);
}

// ---------------- 128x128 MFMA GEMM, A[M][K], B[N][K] (both bf16) ----------------
// Staging: global_load_lds width=16 (m97 pattern, 2-barrier K-loop).
// NSPLIT==3: acc += Ah*Bh + Ah*Bl + Al*Bh   (split-bf16 ~fp32 precision)
// EPI 0: fp32 -> [b, 32 heads, s, hd]+bias (fused Q|K output; heads 0-15=Q, 16-31=K)
// EPI 1: bf16 -> [b,h,hd,s]+bias | EPI 2: fp32 [m][n]+bias
template<int NSPLIT, int EPI>
__global__ __launch_bounds__(256, 2)
void gemm128(const u16* __restrict__ Ah, const u16* __restrict__ Al,
             const u16* __restrict__ Bh, const u16* __restrict__ Bl,
             const float* __restrict__ bias, float* __restrict__ outF,
             u16* __restrict__ outB){
  constexpr int NBUF = (NSPLIT==3) ? 4 : 2;
  __shared__ u16 lds[NBUF * 4096];
  const int tid = threadIdx.x, w = tid >> 6, lane = tid & 63;
  const int wm = w & 1, wn = w >> 1;
  const int m0 = blockIdx.x * 128, n0 = blockIdx.y * 128;
  const int q = lane >> 4, rr = lane & 15;

  const int c0 = w*2, c1 = w*2 + 1;
  const int row0 = c0*16 + (lane >> 2), row1 = c1*16 + (lane >> 2);
  const int g0 = (lane & 3) ^ ((row0 >> 1) & 3);
  const int g1 = (lane & 3) ^ ((row1 >> 1) & 3);
  const size_t a0 = (size_t)(m0 + row0)*1024 + g0*8;
  const size_t a1 = (size_t)(m0 + row1)*1024 + g1*8;
  const size_t b0 = (size_t)(n0 + row0)*1024 + g0*8;
  const size_t b1 = (size_t)(n0 + row1)*1024 + g1*8;

  f32x4 acc[4][4];
  #pragma unroll
  for (int i=0;i<4;i++)
    #pragma unroll
    for (int j=0;j<4;j++) acc[i][j] = f32x4{0.f,0.f,0.f,0.f};

  for (int kt=0; kt<32; kt++){
    const int k0 = kt*32;
    gl_lds16(Ah + a0 + k0, lds + 0*4096 + c0*512);
    gl_lds16(Ah + a1 + k0, lds + 0*4096 + c1*512);
    gl_lds16(Bh + b0 + k0, lds + 1*4096 + c0*512);
    gl_lds16(Bh + b1 + k0, lds + 1*4096 + c1*512);
    if constexpr (NSPLIT == 3){
      gl_lds16(Al + a0 + k0, lds + 2*4096 + c0*512);
      gl_lds16(Al + a1 + k0, lds + 2*4096 + c1*512);
      gl_lds16(Bl + b0 + k0, lds + 3*4096 + c0*512);
      gl_lds16(Bl + b1 + k0, lds + 3*4096 + c1*512);
    }
    __syncthreads();   // drains vmcnt -> staged data visible

    short8 afh[4], bfh[4], afl[4], bfl[4];
    #pragma unroll
    for (int i=0;i<4;i++){
      int r  = wm*64 + i*16 + rr;
      int o  = r*32 + ((q ^ ((r >> 1) & 3))*8);
      afh[i] = *(const short8*)(lds + 0*4096 + o);
      if constexpr (NSPLIT == 3) afl[i] = *(const short8*)(lds + 2*4096 + o);
      int rn = wn*64 + i*16 + rr;
      int on = rn*32 + ((q ^ ((rn >> 1) & 3))*8);
      bfh[i] = *(const short8*)(lds + 1*4096 + on);
      if constexpr (NSPLIT == 3) bfl[i] = *(const short8*)(lds + 3*4096 + on);
    }
    #pragma unroll
    for (int i=0;i<4;i++)
      #pragma unroll
      for (int j=0;j<4;j++){
        acc[i][j] = mfma16(afh[i], bfh[j], acc[i][j]);
        if constexpr (NSPLIT == 3){
          acc[i][j] = mfma16(afh[i], bfl[j], acc[i][j]);
          acc[i][j] = mfma16(afl[i], bfh[j], acc[i][j]);
        }
      }
    __syncthreads();   // protect LDS from next kt's DMA
  }

  #pragma unroll
  for (int i=0;i<4;i++){
    #pragma unroll
    for (int j=0;j<4;j++){
      int n  = n0 + wn*64 + j*16 + rr;
      float bb = bias[n];
      if constexpr (EPI == 1){
        int mb = m0 + wm*64 + i*16 + q*4;
        us4 pk;
        #pragma unroll
        for (int r4=0;r4<4;r4++) pk[r4] = f2bf(acc[i][j][r4] + bb);
        *(us4*)(outB + ((size_t)((mb >> 12)*H_ + (n >> 6))*HD_ + (n & 63))*S_ + (mb & 4095)) = pk;
      } else {
        #pragma unroll
        for (int r4=0;r4<4;r4++){
          int m = m0 + wm*64 + i*16 + q*4 + r4;
          float v = acc[i][j][r4] + bb;
          if constexpr (EPI == 0)
            outF[((size_t)((m >> 12)*32 + (n >> 6)))*S_*HD_ + (size_t)(m & 4095)*HD_ + (n & 63)] = v;
          else
            outF[(size_t)m*1024 + n] = v;
        }
      }
    }
  }
}

// ---------------- fused k-feature + kv' split-K partial, R-SPLIT (R9-exact) --------
// grid (SPLITK_, BH_, 2); block covers 512 s rows x HALF the R features (128 rows).
// kv rows DISJOINT across th -> both halves write disjoint rows of kvp16.
// LDS = kp 18 KB + rf half 32 KB = 50 KB -> multi-block/CU TLP (the R9 win).
// K rows read from fused qk32 layout: head base (b*32 + 16 + h).
__global__ __launch_bounds__(256, 1)
void kfeat_kv_kernel(const float* __restrict__ qk32,
                     const u16* __restrict__ rfh, const u16* __restrict__ rfl,
                     const u16* __restrict__ vt, u16* __restrict__ kvp16){
  __shared__ u16 kp[128*72];
  __shared__ u16 lrfh[128*HD_];
  __shared__ u16 lrfl[128*HD_];
  const int sp = blockIdx.x, hb = blockIdx.y, th = blockIdx.z, h = hb & 15;
  const int tid = threadIdx.x, w = tid >> 6, lane = tid & 63;
  const int q = lane >> 4, rr = lane & 15;
  const int sw8 = rr & 7;
  const float* kbp = qk32 + (size_t)((hb >> 4)*32 + 16 + h)*S_*HD_;   // K head base

  stage_rf_half(rfh, rfl, h, th, tid, w, lrfh, lrfl);

  short8 ones;
  { u16 one = (rr == 0) ? (u16)0x3F80 : (u16)0;
    #pragma unroll
    for (int j=0;j<8;j++) ones[j] = (short)one; }

  f32x4 acc2[2][5];
  #pragma unroll
  for (int a=0;a<2;a++)
    #pragma unroll
    for (int t=0;t<5;t++) acc2[a][t] = f32x4{0.f,0.f,0.f,0.f};

  __syncthreads();   // rf staged (drains DMA)

  // preload sub 0's k rows
  const float* ap0 = kbp + (size_t)(sp*(S_/SPLITK_) + w*16 + rr)*HD_ + q*8;
  float4 x0 = *(const float4*)(ap0);
  float4 x1 = *(const float4*)(ap0 + 4);
  float4 x2 = *(const float4*)(ap0 + 32);
  float4 x3 = *(const float4*)(ap0 + 36);

  for (int sub=0; sub<(S_/SPLITK_)/64; sub++){
    const int s0 = sp*(S_/SPLITK_) + sub*64;
    float sql[4];
    rowsq(x0, x1, x2, x3, q, sql);
    short8 ah[2], al[2];
    cvt8(x0, x1, ah[0], al[0]);
    cvt8(x2, x3, ah[1], al[1]);
    if (sub < (S_/SPLITK_)/64 - 1){   // prefetch next sub's k rows
      const float* apn = kbp + (size_t)(s0 + 64 + w*16 + rr)*HD_ + q*8;
      x0 = *(const float4*)(apn);
      x1 = *(const float4*)(apn + 4);
      x2 = *(const float4*)(apn + 32);
      x3 = *(const float4*)(apn + 36);
    }

    f32x4 accp[8];
    #pragma unroll
    for (int tt=0;tt<8;tt++) accp[tt] = f32x4{0.f,0.f,0.f,0.f};
    #pragma unroll
    for (int tt=0;tt<8;tt++){
      const u16* lrow  = lrfh + (tt*16 + rr)*64;
      const u16* lrowl = lrfl + (tt*16 + rr)*64;
      short8 bh0 = *(const short8*)(lrow  + ((q     ^ sw8))*8);
      short8 bh1 = *(const short8*)(lrow  + (((q+4) ^ sw8))*8);
      short8 bl0 = *(const short8*)(lrowl + ((q     ^ sw8))*8);
      short8 bl1 = *(const short8*)(lrowl + (((q+4) ^ sw8))*8);
      f32x4 c = accp[tt];
      c = mfma16(ah[0], bh0, c); c = mfma16(ah[0], bl0, c); c = mfma16(al[0], bh0, c);
      c = mfma16(ah[1], bh1, c); c = mfma16(ah[1], bl1, c); c = mfma16(al[1], bh1, c);
      accp[tt] = c;
    }
    #pragma unroll
    for (int tt=0;tt<8;tt++){
      us4 pk;
      #pragma unroll
      for (int r4=0;r4<4;r4++) pk[r4] = f2bf(__expf(accp[tt][r4] - sql[r4]));
      *(us4*)(kp + (tt*16 + rr)*72 + w*16 + q*4) = pk;
    }
    __syncthreads();
    #pragma unroll
    for (int ks=0; ks<2; ks++){
      short8 af[2];
      #pragma unroll
      for (int a=0;a<2;a++)
        af[a] = *(const short8*)(kp + (w*32 + a*16 + rr)*72 + ks*32 + q*8);
      #pragma unroll
      for (int t=0;t<5;t++){
        short8 bf;
        if (t < 4)
          bf = *(const short8*)(vt + ((size_t)hb*HD_ + t*16 + rr)*S_ + s0 + ks*32 + q*8);
        else
          bf = ones;
        #pragma unroll
        for (int a=0;a<2;a++) acc2[a][t] = mfma16(af[a], bf, acc2[a][t]);
      }
    }
    __syncthreads();
  }
  u16* op = kvp16 + ((size_t)hb*SPLITK_ + sp)*R_*80;
  #pragma unroll
  for (int a=0;a<2;a++)
    #pragma unroll
    for (int t=0;t<5;t++)
      #pragma unroll
      for (int r4=0;r4<4;r4++){
        int r = th*128 + w*32 + a*16 + q*4 + r4;
        int c = t*16 + rr;
        op[r*80 + c] = f2bf(acc2[a][t][r4]);
      }
}

// reduce bf16 kv partials: kv_t[hb][d][r] bf16, ksum[hb][r] fp32
__global__ void kv_reduce_kernel(const u16* __restrict__ kvp16, u16* __restrict__ kvt,
                                 float* __restrict__ ksum){
  int r = blockIdx.x, hb = blockIdx.y, c = threadIdx.x;
  if (c >= 65) return;
  const u16* base = kvp16 + (size_t)hb*SPLITK_*R_*80 + r*80 + c;
  float s = 0.f;
  #pragma unroll
  for (int sp=0; sp<SPLITK_; sp++) s += bf2f(base[(size_t)sp*R_*80]);
  if (c < 64) kvt[((size_t)hb*HD_ + c)*R_ + r] = f2bf(s);
  else        ksum[(size_t)hb*R_ + r] = s;
}

// ---------------- fused q-feature + attn + norm ----------------
// grid (4, BH_) = 256 blocks = EXACTLY 1/CU: the 96 KB rf+kvt stage happens once
// per CU (was twice at grid 8), no tail. Block covers 1024 s rows, 16 sub-chunks.
// kvt[hb] (32 KB) LDS-staged XOR-swizzled (R10 win); rf hi+lo LDS-staged (R6 win);
// qp wave-private -> no barriers in sub loop. LDS 129.8 KB, bounds(256,1) natural alloc.
// Q rows read from fused qk32 layout: head base (b*32 + h).
__global__ __launch_bounds__(256, 1)
void qfeat_attn_kernel(const float* __restrict__ qk32,
                       const u16* __restrict__ rfh, const u16* __restrict__ rfl,
                       const u16* __restrict__ kvt, const float* __restrict__ ksum,
                       u16* __restrict__ attn_c){
  __shared__ u16 qp[64*264];
  __shared__ u16 lrfh[R_*HD_];
  __shared__ u16 lrfl[R_*HD_];
  __shared__ u16 lkvt[HD_*R_];      // 64 d-rows x 256 r, 32 KB
  const int sc = blockIdx.x, hb = blockIdx.y, h = hb & 15, b = hb >> 4;
  const int tid = threadIdx.x, w = tid >> 6, lane = tid & 63;
  const int q = lane >> 4, rr = lane & 15;
  const int sw8 = rr & 7;
  const float* qbp = qk32 + (size_t)(b*32 + h)*S_*HD_;   // Q head base

  stage_rf_full(rfh, rfl, h, tid, w, lrfh, lrfl);
  // stage kvt[hb] (64 rows x 256 u16 = 512B rows, 32 groups of 16B each):
  // slot gd holds global group gd ^ (row&7); read side XORs identically.
  {
    const u16* kg = kvt + (size_t)hb*HD_*R_;
    #pragma unroll
    for (int c=0;c<8;c++){
      int idx = c*256 + tid;          // 0..2047 <-> (row 0..63, group 0..31)
      int row = idx >> 5, gd = idx & 31;
      int gs  = gd ^ (row & 7);
      gl_lds16(kg + row*256 + gs*8, lkvt + c*2048 + w*512);
    }
  }

  float kslv[16];
  #pragma unroll
  for (int t=0;t<16;t++) kslv[t] = ksum[(size_t)hb*R_ + t*16 + rr];

  __syncthreads();   // rf + kvt staged (drains DMA)

  // preload sub 0's q rows
  const float* ap0 = qbp + (size_t)(sc*1024 + w*16 + rr)*HD_ + q*8;
  float4 x0 = *(const float4*)(ap0);
  float4 x1 = *(const float4*)(ap0 + 4);
  float4 x2 = *(const float4*)(ap0 + 32);
  float4 x3 = *(const float4*)(ap0 + 36);

  for (int sub=0; sub<16; sub++){
    const int s0 = sc*1024 + sub*64;
    // ---- phase 1: q' for 64 s rows ----
    float sql[4];
    rowsq(x0, x1, x2, x3, q, sql);
    short8 ah[2], al[2];
    cvt8(x0, x1, ah[0], al[0]);
    cvt8(x2, x3, ah[1], al[1]);
    if (sub < 15){   // prefetch next sub's q rows (completes under phase 1+2)
      const float* apn = qbp + (size_t)(s0 + 64 + w*16 + rr)*HD_ + q*8;
      x0 = *(const float4*)(apn);
      x1 = *(const float4*)(apn + 4);
      x2 = *(const float4*)(apn + 32);
      x3 = *(const float4*)(apn + 36);
    }

    f32x4 accp[16];
    #pragma unroll
    for (int t=0;t<16;t++) accp[t] = f32x4{0.f,0.f,0.f,0.f};
    #pragma unroll
    for (int t=0;t<16;t++){
      const u16* lrow  = lrfh + (t*16 + rr)*64;
      const u16* lrowl = lrfl + (t*16 + rr)*64;
      short8 bh0 = *(const short8*)(lrow  + ((q     ^ sw8))*8);
      short8 bh1 = *(const short8*)(lrow  + (((q+4) ^ sw8))*8);
      short8 bl0 = *(const short8*)(lrowl + ((q     ^ sw8))*8);
      short8 bl1 = *(const short8*)(lrowl + (((q+4) ^ sw8))*8);
      f32x4 c = accp[t];
      c = mfma16(ah[0], bh0, c); c = mfma16(ah[0], bl0, c); c = mfma16(al[0], bh0, c);
      c = mfma16(ah[1], bh1, c); c = mfma16(ah[1], bl1, c); c = mfma16(al[1], bh1, c);
      accp[t] = c;
    }
    // exp -> qp (A-layout staging) + in-register norm partials
    float npl[4] = {0.f, 0.f, 0.f, 0.f};
    #pragma unroll
    for (int t=0;t<16;t++){
      us4 pk;
      #pragma unroll
      for (int r4=0;r4<4;r4++){
        float e = __expf(accp[t][r4] - sql[r4]);
        npl[r4] += e * kslv[t];
        pk[r4] = f2bf(e);
      }
      #pragma unroll
      for (int r4=0;r4<4;r4++)
        qp[(w*16 + q*4 + r4)*264 + t*16 + rr] = pk[r4];
    }
    // reduce norm over rr (bits 0-3 of lane) -> lanes keep rows q*4+r4
    #pragma unroll
    for (int r4=0;r4<4;r4++){
      npl[r4] += __shfl_xor(npl[r4], 1);
      npl[r4] += __shfl_xor(npl[r4], 2);
      npl[r4] += __shfl_xor(npl[r4], 4);
      npl[r4] += __shfl_xor(npl[r4], 8);
    }
    // no barrier: qp rows read below are the ones this wave just wrote (in-order DS)

    // ---- phase 2: attn = q' @ kv'^T ; wave w owns s rows w*16..w*16+15 ----
    f32x4 acc[4];
    #pragma unroll
    for (int t=0;t<4;t++) acc[t] = f32x4{0.f,0.f,0.f,0.f};
    #pragma unroll
    for (int ks=0; ks<8; ks++){
      short8 af = *(const short8*)(qp + (w*16 + rr)*264 + ks*32 + q*8);
      #pragma unroll
      for (int t=0;t<4;t++){
        short8 bf = *(const short8*)(lkvt + (t*16 + rr)*256 + (((ks*4 + q) ^ sw8))*8);
        acc[t] = mfma16(af, bf, acc[t]);
      }
    }

    #pragma unroll
    for (int t=0;t<4;t++)
      #pragma unroll
      for (int r4=0;r4<4;r4++){
        int sl = w*16 + q*4 + r4;
        int d  = t*16 + rr;
        float o = acc[t][r4] / (npl[r4] + 1e-6f);
        attn_c[((size_t)b*S_ + s0 + sl)*D_ + h*HD_ + d] = f2bf(o);
      }
    // no trailing barrier: next sub's qp writes are same-wave, in-order
  }
}

// ---------------- host ----------------
extern "C" void kernel_launch(void* const* d_in, const int* in_sizes, int n_in,
                              void* d_out, int out_size, void* d_ws, size_t ws_size,
                              hipStream_t stream){
  (void)in_sizes; (void)n_in; (void)out_size; (void)ws_size;
  const float* x  = (const float*)d_in[0];
  const float* wq = (const float*)d_in[1];
  const float* bq = (const float*)d_in[2];
  const float* wk = (const float*)d_in[3];
  const float* bk = (const float*)d_in[4];
  const float* wv = (const float*)d_in[5];
  const float* bv = (const float*)d_in[6];
  const float* wo = (const float*)d_in[7];
  const float* bo = (const float*)d_in[8];
  const float* rf = (const float*)d_in[9];
  float* out = (float*)d_out;

  char* p = (char*)d_ws;
  size_t off = 0;
  auto take = [&](size_t bytes)->char*{
    char* r = p + off; off += (bytes + 255) & ~(size_t)255; return r;
  };
  u16*  x_hi   = (u16*)take((size_t)M_*D_*2);
  u16*  x_lo   = (u16*)take((size_t)M_*D_*2);
  u16*  wqk_hi = (u16*)take((size_t)2*D_*D_*2);   // [wq ; wk] rows 0-2047
  u16*  wqk_lo = (u16*)take((size_t)2*D_*D_*2);
  u16*  wv_hi  = (u16*)take((size_t)D_*D_*2);
  u16*  wo_hi  = (u16*)take((size_t)D_*D_*2);
  u16*  rf_hi  = (u16*)take((size_t)H_*R_*HD_*2);
  u16*  rf_lo  = (u16*)take((size_t)H_*R_*HD_*2);
  float* bqk   = (float*)take((size_t)2048*4);
  float* qk32  = (float*)take((size_t)M_*2048*4); // [b][32 heads][s][hd]
  u16*  v_t    = (u16*)take((size_t)M_*D_*2);
  u16*  kvt    = (u16*)take((size_t)BH_*HD_*R_*2);
  float* ksum  = (float*)take((size_t)BH_*R_*4);
  // aliases (stream-ordered reuse of dead buffers):
  u16* attn_c = x_hi;   // x_hi dead after V projection
  u16* kvp16  = x_lo;   // x_lo dead after fused QK projection; 21 MB <= 33.5 MB

  // prep: all splits + bias concat in ONE launch
  prep_kernel<<<dim3(XB_ + 4*WB_ + 1024 + 8), 256, 0, stream>>>(
      x, wq, wk, wv, wo, rf, bq, bk,
      x_hi, x_lo, wqk_hi, wqk_lo, wv_hi, wo_hi, rf_hi, rf_lo, bqk);

  // fused Q|K projection (N=2048): A-panels read once instead of twice
  gemm128<3,0><<<dim3(M_/128, 2048/128), 256, 0, stream>>>(x_hi, x_lo, wqk_hi, wqk_lo, bqk, qk32, nullptr);
  // V projection
  gemm128<1,1><<<dim3(M_/128, D_/128), 256, 0, stream>>>(x_hi, nullptr, wv_hi, nullptr, bv, nullptr, v_t);

  // k' -> kv partials (R-split across z) -> reduce
  kfeat_kv_kernel<<<dim3(SPLITK_, BH_, 2), 256, 0, stream>>>(qk32, rf_hi, rf_lo, v_t, kvp16);
  kv_reduce_kernel<<<dim3(R_, BH_), 128, 0, stream>>>(kvp16, kvt, ksum);

  // q' -> attn -> attn_c
  qfeat_attn_kernel<<<dim3(4, BH_), 256, 0, stream>>>(qk32, rf_hi, rf_lo, kvt, ksum, attn_c);

  // output projection
  gemm128<1,2><<<dim3(M_/128, D_/128), 256, 0, stream>>>(attn_c, nullptr, wo_hi, nullptr, bo, out, nullptr);
}

// Round 13
// 576.297 us; speedup vs baseline: 1.3791x; 1.0222x over previous
//
#include <hip/hip_runtime.h>
#include <stdint.h>

#define B_  4
#define S_  4096
#define D_  1024
#define H_  16
#define R_  256
#define HD_ 64
#define BH_ 64        // B_*H_
#define M_  16384     // B_*S_
#define SPLITK_ 8     // kv split-K partials, bf16: 8*64*256*80*2 = 21 MB <= x_lo (33.5 MB)

typedef uint16_t u16;
typedef __attribute__((ext_vector_type(8))) short short8;
typedef __attribute__((ext_vector_type(4))) float f32x4;
typedef __attribute__((ext_vector_type(4))) unsigned short us4;

__device__ __forceinline__ u16 f2bf(float f){
  union { float f; uint32_t u; } v; v.f = f;
  uint32_t r = v.u + 0x7FFFu + ((v.u >> 16) & 1u);
  return (u16)(r >> 16);
}
__device__ __forceinline__ float bf2f(u16 h){
  union { uint32_t u; float f; } v; v.u = ((uint32_t)h) << 16;
  return v.f;
}
__device__ __forceinline__ f32x4 mfma16(short8 a, short8 b, f32x4 c){
  return __builtin_amdgcn_mfma_f32_16x16x32_bf16(a, b, c, 0, 0, 0);
}
// async global->LDS DMA, 16B per lane; LDS dest = wave-uniform base + lane*16,
// global source address is PER-LANE (enables pre-swizzled staging, rule #21)
__device__ __forceinline__ void gl_lds16(const u16* g, u16* l){
  __builtin_amdgcn_global_load_lds((const __attribute__((address_space(1))) void*)g,
                                   (__attribute__((address_space(3))) void*)l, 16, 0, 0);
}
// split a float8 (two float4) into bf16 hi + lo fragments
__device__ __forceinline__ void cvt8(const float4& a, const float4& b, short8& hi, short8& lo){
  float f[8] = {a.x,a.y,a.z,a.w,b.x,b.y,b.z,b.w};
  #pragma unroll
  for (int j=0;j<8;j++){
    u16 h = f2bf(f[j]);
    hi[j] = (short)h;
    lo[j] = (short)f2bf(f[j] - bf2f(h));
  }
}

// Stage rf_hi/rf_lo (full 256 rows) for one head into LDS, bank-swizzle
// gs = gd ^ (row&7) applied on the GLOBAL source address (LDS dest stays linear,
// rule #21). Read side XORs the same way. 256-thread blocks.
__device__ __forceinline__ void stage_rf_full(const u16* __restrict__ rfh,
                                              const u16* __restrict__ rfl,
                                              int h, int tid, int w,
                                              u16* lrfh, u16* lrfl){
  const u16* baseH = rfh + (size_t)h*(R_*HD_);
  const u16* baseL = rfl + (size_t)h*(R_*HD_);
  #pragma unroll
  for (int c=0;c<8;c++){
    int idx = c*256 + tid;            // 0..2047 <-> (row 0..255, group 0..7)
    int row = idx >> 3, gd = idx & 7;
    int gs  = gd ^ (row & 7);         // inverse swizzle on source
    gl_lds16(baseH + row*64 + gs*8, lrfh + c*2048 + w*512);
    gl_lds16(baseL + row*64 + gs*8, lrfl + c*2048 + w*512);
  }
}

// Stage a 128-row HALF of rf_hi/rf_lo (rows [th*128, th*128+128)), same swizzle.
__device__ __forceinline__ void stage_rf_half(const u16* __restrict__ rfh,
                                              const u16* __restrict__ rfl,
                                              int h, int th, int tid, int w,
                                              u16* lrfh, u16* lrfl){
  const u16* baseH = rfh + (size_t)h*(R_*HD_) + (size_t)th*128*HD_;
  const u16* baseL = rfl + (size_t)h*(R_*HD_) + (size_t)th*128*HD_;
  #pragma unroll
  for (int c=0;c<4;c++){
    int idx = c*256 + tid;            // 0..1023 <-> (row 0..127, group 0..7)
    int row = idx >> 3, gd = idx & 7;
    int gs  = gd ^ (row & 7);         // row&7 == global row&7 (half is 128-aligned)
    gl_lds16(baseH + row*64 + gs*8, lrfh + c*2048 + w*512);
    gl_lds16(baseL + row*64 + gs*8, lrfl + c*2048 + w*512);
  }
}

// ---------------- merged prep kernel ----------------
// One launch handles: x split, wq/wk splits (into concatenated wqk), wv/wo hi-only
// splits, rf transpose-split, and the [bq|bk] bias concat. Region dispatch on
// blockIdx.x (block-uniform branch). Saves 5 launch gaps vs separate kernels.
#define XB_ ((M_*D_)/1024)   // 16384 blocks
#define WB_ ((D_*D_)/1024)   // 1024 blocks per weight
__device__ __forceinline__ void split_body(const float* __restrict__ src,
                                           u16* __restrict__ hi, u16* __restrict__ lo,
                                           int bid, int tid){
  int i = bid*256 + tid;   // float4 index (regions are exact multiples of 256)
  float4 f = ((const float4*)src)[i];
  float ff[4] = {f.x,f.y,f.z,f.w};
  us4 hv, lv;
  #pragma unroll
  for (int j=0;j<4;j++){
    u16 h = f2bf(ff[j]);
    hv[j] = h;
    lv[j] = f2bf(ff[j] - bf2f(h));
  }
  ((us4*)hi)[i] = hv;
  if (lo) ((us4*)lo)[i] = lv;
}
__global__ void prep_kernel(const float* __restrict__ x,  const float* __restrict__ wq,
                            const float* __restrict__ wk, const float* __restrict__ wv,
                            const float* __restrict__ wo, const float* __restrict__ rf,
                            const float* __restrict__ bq, const float* __restrict__ bk,
                            u16* __restrict__ x_hi, u16* __restrict__ x_lo,
                            u16* __restrict__ wqk_hi, u16* __restrict__ wqk_lo,
                            u16* __restrict__ wv_hi, u16* __restrict__ wo_hi,
                            u16* __restrict__ rf_hi, u16* __restrict__ rf_lo,
                            float* __restrict__ bqk){
  int bid = blockIdx.x, tid = threadIdx.x;
  if (bid < XB_){ split_body(x, x_hi, x_lo, bid, tid); return; }
  bid -= XB_;
  if (bid < WB_){ split_body(wq, wqk_hi, wqk_lo, bid, tid); return; }
  bid -= WB_;
  if (bid < WB_){ split_body(wk, wqk_hi + (size_t)D_*D_, wqk_lo + (size_t)D_*D_, bid, tid); return; }
  bid -= WB_;
  if (bid < WB_){ split_body(wv, wv_hi, nullptr, bid, tid); return; }
  bid -= WB_;
  if (bid < WB_){ split_body(wo, wo_hi, nullptr, bid, tid); return; }
  bid -= WB_;
  if (bid < 1024){
    // rf [H][HD][R] fp32 -> rf_t hi/lo [H][R][HD] bf16
    int idx = bid*256 + tid;          // over H*R*HD = 262144
    int d = idx & 63, r = (idx >> 6) & 255, h = idx >> 14;
    float f = rf[((size_t)h*HD_ + d)*R_ + r];
    u16 hh = f2bf(f);
    rf_hi[idx] = hh;
    rf_lo[idx] = f2bf(f - bf2f(hh));
    return;
  }
  bid -= 1024;
  int i = bid*256 + tid;              // bias concat, 2048 floats (8 blocks)
  if (i < 1024)       bqk[i] = bq[i];
  else if (i < 2048)  bqk[i] = bk[i - 1024];
}

// fused ||row||^2/2: lane (q,rr) holds 16 elems of row w*16+rr.
// result sql[r4] = 0.5*||row w*16+q*4+r4||^2 on every lane (matches C-layout rows).
__device__ __forceinline__ void rowsq(const float4& x0, const float4& x1,
                                      const float4& x2, const float4& x3,
                                      int q, float sql[4]){
  float s = x0.x*x0.x + x0.y*x0.y + x0.z*x0.z + x0.w*x0.w
          + x1.x*x1.x + x1.y*x1.y + x1.z*x1.z + x1.w*x1.w
          + x2.x*x2.x + x2.y*x2.y + x2.z*x2.z + x2.w*x2.w
          + x3.x*x3.x + x3.y*x3.y + x3.z*x3.z + x3.w*x3.w;
  s += __shfl_xor(s, 16);
  s += __shfl_xor(s, 32);
  #pragma unroll
  for (int r4=0;r4<4;r4++) sql[r4] = 0.5f * __shfl(s, q*4 + r4);
}

// ---------------- 128x128 MFMA GEMM, A[M][K], B[N][K] (both bf16) ----------------
// Staging: global_load_lds width=16 (m97 pattern, 2-barrier K-loop).
// NSPLIT==3: acc += Ah*Bh + Ah*Bl + Al*Bh   (split-bf16 ~fp32 precision)
// EPI 0: fp32 -> [b, 32 heads, s, hd]+bias (fused Q|K output; heads 0-15=Q, 16-31=K)
// EPI 1: bf16 -> [b,h,hd,s]+bias | EPI 2: fp32 [m][n]+bias
// SWZ 1 (requires grid exactly (128,16)): L2-locality remap — each XCD (dispatch id
// mod 8) owns a contiguous 16-wide x-chunk; within it, 4-x-panel x 16-y sub-groups
// keep 4 A-panels (2 MB hi+lo) + B panels resident in the XCD's 4 MB L2 across all
// 16 y-tiles, instead of evicting A between y-sweeps (FETCH 220 MB vs 144 ideal).
// Bijective: n in [0,2048) <-> (c,g,xo,yy). Pure index permutation, no sync change.
template<int NSPLIT, int EPI, int SWZ>
__global__ __launch_bounds__(256, 2)
void gemm128(const u16* __restrict__ Ah, const u16* __restrict__ Al,
             const u16* __restrict__ Bh, const u16* __restrict__ Bl,
             const float* __restrict__ bias, float* __restrict__ outF,
             u16* __restrict__ outB){
  constexpr int NBUF = (NSPLIT==3) ? 4 : 2;
  __shared__ u16 lds[NBUF * 4096];
  const int tid = threadIdx.x, w = tid >> 6, lane = tid & 63;
  const int wm = w & 1, wn = w >> 1;
  int m0, n0;
  if constexpr (SWZ){
    int n  = blockIdx.y*128 + blockIdx.x;  // dispatch-order linear id (x fastest)
    int c  = n & 7;                        // XCD
    int j  = n >> 3;                       // 0..255 within XCD
    int g  = j >> 6;                       // x-sub-chunk of 4 (0..3)
    int t  = j & 63;
    int yy = t >> 2;                       // 0..15
    int xo = t & 3;
    m0 = (c*16 + g*4 + xo)*128;
    n0 = yy*128;
  } else {
    m0 = blockIdx.x * 128;
    n0 = blockIdx.y * 128;
  }
  const int q = lane >> 4, rr = lane & 15;

  const int c0 = w*2, c1 = w*2 + 1;
  const int row0 = c0*16 + (lane >> 2), row1 = c1*16 + (lane >> 2);
  const int g0 = (lane & 3) ^ ((row0 >> 1) & 3);
  const int g1 = (lane & 3) ^ ((row1 >> 1) & 3);
  const size_t a0 = (size_t)(m0 + row0)*1024 + g0*8;
  const size_t a1 = (size_t)(m0 + row1)*1024 + g1*8;
  const size_t b0 = (size_t)(n0 + row0)*1024 + g0*8;
  const size_t b1 = (size_t)(n0 + row1)*1024 + g1*8;

  f32x4 acc[4][4];
  #pragma unroll
  for (int i=0;i<4;i++)
    #pragma unroll
    for (int j=0;j<4;j++) acc[i][j] = f32x4{0.f,0.f,0.f,0.f};

  for (int kt=0; kt<32; kt++){
    const int k0 = kt*32;
    gl_lds16(Ah + a0 + k0, lds + 0*4096 + c0*512);
    gl_lds16(Ah + a1 + k0, lds + 0*4096 + c1*512);
    gl_lds16(Bh + b0 + k0, lds + 1*4096 + c0*512);
    gl_lds16(Bh + b1 + k0, lds + 1*4096 + c1*512);
    if constexpr (NSPLIT == 3){
      gl_lds16(Al + a0 + k0, lds + 2*4096 + c0*512);
      gl_lds16(Al + a1 + k0, lds + 2*4096 + c1*512);
      gl_lds16(Bl + b0 + k0, lds + 3*4096 + c0*512);
      gl_lds16(Bl + b1 + k0, lds + 3*4096 + c1*512);
    }
    __syncthreads();   // drains vmcnt -> staged data visible

    short8 afh[4], bfh[4], afl[4], bfl[4];
    #pragma unroll
    for (int i=0;i<4;i++){
      int r  = wm*64 + i*16 + rr;
      int o  = r*32 + ((q ^ ((r >> 1) & 3))*8);
      afh[i] = *(const short8*)(lds + 0*4096 + o);
      if constexpr (NSPLIT == 3) afl[i] = *(const short8*)(lds + 2*4096 + o);
      int rn = wn*64 + i*16 + rr;
      int on = rn*32 + ((q ^ ((rn >> 1) & 3))*8);
      bfh[i] = *(const short8*)(lds + 1*4096 + on);
      if constexpr (NSPLIT == 3) bfl[i] = *(const short8*)(lds + 3*4096 + on);
    }
    #pragma unroll
    for (int i=0;i<4;i++)
      #pragma unroll
      for (int j=0;j<4;j++){
        acc[i][j] = mfma16(afh[i], bfh[j], acc[i][j]);
        if constexpr (NSPLIT == 3){
          acc[i][j] = mfma16(afh[i], bfl[j], acc[i][j]);
          acc[i][j] = mfma16(afl[i], bfh[j], acc[i][j]);
        }
      }
    __syncthreads();   // protect LDS from next kt's DMA
  }

  #pragma unroll
  for (int i=0;i<4;i++){
    #pragma unroll
    for (int j=0;j<4;j++){
      int n  = n0 + wn*64 + j*16 + rr;
      float bb = bias[n];
      if constexpr (EPI == 1){
        int mb = m0 + wm*64 + i*16 + q*4;
        us4 pk;
        #pragma unroll
        for (int r4=0;r4<4;r4++) pk[r4] = f2bf(acc[i][j][r4] + bb);
        *(us4*)(outB + ((size_t)((mb >> 12)*H_ + (n >> 6))*HD_ + (n & 63))*S_ + (mb & 4095)) = pk;
      } else {
        #pragma unroll
        for (int r4=0;r4<4;r4++){
          int m = m0 + wm*64 + i*16 + q*4 + r4;
          float v = acc[i][j][r4] + bb;
          if constexpr (EPI == 0)
            outF[((size_t)((m >> 12)*32 + (n >> 6)))*S_*HD_ + (size_t)(m & 4095)*HD_ + (n & 63)] = v;
          else
            outF[(size_t)m*1024 + n] = v;
        }
      }
    }
  }
}

// ---------------- fused k-feature + kv' split-K partial, R-SPLIT (R9-exact) --------
// grid (SPLITK_, BH_, 2); block covers 512 s rows x HALF the R features (128 rows).
// kv rows DISJOINT across th -> both halves write disjoint rows of kvp16.
// LDS = kp 18 KB + rf half 32 KB = 50 KB -> multi-block/CU TLP (the R9 win).
// K rows read from fused qk32 layout: head base (b*32 + 16 + h).
__global__ __launch_bounds__(256, 1)
void kfeat_kv_kernel(const float* __restrict__ qk32,
                     const u16* __restrict__ rfh, const u16* __restrict__ rfl,
                     const u16* __restrict__ vt, u16* __restrict__ kvp16){
  __shared__ u16 kp[128*72];
  __shared__ u16 lrfh[128*HD_];
  __shared__ u16 lrfl[128*HD_];
  const int sp = blockIdx.x, hb = blockIdx.y, th = blockIdx.z, h = hb & 15;
  const int tid = threadIdx.x, w = tid >> 6, lane = tid & 63;
  const int q = lane >> 4, rr = lane & 15;
  const int sw8 = rr & 7;
  const float* kbp = qk32 + (size_t)((hb >> 4)*32 + 16 + h)*S_*HD_;   // K head base

  stage_rf_half(rfh, rfl, h, th, tid, w, lrfh, lrfl);

  short8 ones;
  { u16 one = (rr == 0) ? (u16)0x3F80 : (u16)0;
    #pragma unroll
    for (int j=0;j<8;j++) ones[j] = (short)one; }

  f32x4 acc2[2][5];
  #pragma unroll
  for (int a=0;a<2;a++)
    #pragma unroll
    for (int t=0;t<5;t++) acc2[a][t] = f32x4{0.f,0.f,0.f,0.f};

  __syncthreads();   // rf staged (drains DMA)

  // preload sub 0's k rows
  const float* ap0 = kbp + (size_t)(sp*(S_/SPLITK_) + w*16 + rr)*HD_ + q*8;
  float4 x0 = *(const float4*)(ap0);
  float4 x1 = *(const float4*)(ap0 + 4);
  float4 x2 = *(const float4*)(ap0 + 32);
  float4 x3 = *(const float4*)(ap0 + 36);

  for (int sub=0; sub<(S_/SPLITK_)/64; sub++){
    const int s0 = sp*(S_/SPLITK_) + sub*64;
    float sql[4];
    rowsq(x0, x1, x2, x3, q, sql);
    short8 ah[2], al[2];
    cvt8(x0, x1, ah[0], al[0]);
    cvt8(x2, x3, ah[1], al[1]);
    if (sub < (S_/SPLITK_)/64 - 1){   // prefetch next sub's k rows
      const float* apn = kbp + (size_t)(s0 + 64 + w*16 + rr)*HD_ + q*8;
      x0 = *(const float4*)(apn);
      x1 = *(const float4*)(apn + 4);
      x2 = *(const float4*)(apn + 32);
      x3 = *(const float4*)(apn + 36);
    }

    f32x4 accp[8];
    #pragma unroll
    for (int tt=0;tt<8;tt++) accp[tt] = f32x4{0.f,0.f,0.f,0.f};
    #pragma unroll
    for (int tt=0;tt<8;tt++){
      const u16* lrow  = lrfh + (tt*16 + rr)*64;
      const u16* lrowl = lrfl + (tt*16 + rr)*64;
      short8 bh0 = *(const short8*)(lrow  + ((q     ^ sw8))*8);
      short8 bh1 = *(const short8*)(lrow  + (((q+4) ^ sw8))*8);
      short8 bl0 = *(const short8*)(lrowl + ((q     ^ sw8))*8);
      short8 bl1 = *(const short8*)(lrowl + (((q+4) ^ sw8))*8);
      f32x4 c = accp[tt];
      c = mfma16(ah[0], bh0, c); c = mfma16(ah[0], bl0, c); c = mfma16(al[0], bh0, c);
      c = mfma16(ah[1], bh1, c); c = mfma16(ah[1], bl1, c); c = mfma16(al[1], bh1, c);
      accp[tt] = c;
    }
    #pragma unroll
    for (int tt=0;tt<8;tt++){
      us4 pk;
      #pragma unroll
      for (int r4=0;r4<4;r4++) pk[r4] = f2bf(__expf(accp[tt][r4] - sql[r4]));
      *(us4*)(kp + (tt*16 + rr)*72 + w*16 + q*4) = pk;
    }
    __syncthreads();
    #pragma unroll
    for (int ks=0; ks<2; ks++){
      short8 af[2];
      #pragma unroll
      for (int a=0;a<2;a++)
        af[a] = *(const short8*)(kp + (w*32 + a*16 + rr)*72 + ks*32 + q*8);
      #pragma unroll
      for (int t=0;t<5;t++){
        short8 bf;
        if (t < 4)
          bf = *(const short8*)(vt + ((size_t)hb*HD_ + t*16 + rr)*S_ + s0 + ks*32 + q*8);
        else
          bf = ones;
        #pragma unroll
        for (int a=0;a<2;a++) acc2[a][t] = mfma16(af[a], bf, acc2[a][t]);
      }
    }
    __syncthreads();
  }
  u16* op = kvp16 + ((size_t)hb*SPLITK_ + sp)*R_*80;
  #pragma unroll
  for (int a=0;a<2;a++)
    #pragma unroll
    for (int t=0;t<5;t++)
      #pragma unroll
      for (int r4=0;r4<4;r4++){
        int r = th*128 + w*32 + a*16 + q*4 + r4;
        int c = t*16 + rr;
        op[r*80 + c] = f2bf(acc2[a][t][r4]);
      }
}

// reduce bf16 kv partials: kv_t[hb][d][r] bf16, ksum[hb][r] fp32
__global__ void kv_reduce_kernel(const u16* __restrict__ kvp16, u16* __restrict__ kvt,
                                 float* __restrict__ ksum){
  int r = blockIdx.x, hb = blockIdx.y, c = threadIdx.x;
  if (c >= 65) return;
  const u16* base = kvp16 + (size_t)hb*SPLITK_*R_*80 + r*80 + c;
  float s = 0.f;
  #pragma unroll
  for (int sp=0; sp<SPLITK_; sp++) s += bf2f(base[(size_t)sp*R_*80]);
  if (c < 64) kvt[((size_t)hb*HD_ + c)*R_ + r] = f2bf(s);
  else        ksum[(size_t)hb*R_ + r] = s;
}

// ---------------- fused q-feature + attn + norm ----------------
// grid (4, BH_) = 256 blocks = EXACTLY 1/CU: the 96 KB rf+kvt stage happens once
// per CU. Block covers 1024 s rows, 16 sub-chunks.
// kvt[hb] (32 KB) LDS-staged XOR-swizzled (R10 win); rf hi+lo LDS-staged (R6 win);
// qp wave-private -> no barriers in sub loop. LDS 129.8 KB, bounds(256,1) natural alloc.
// Q rows read from fused qk32 layout: head base (b*32 + h).
__global__ __launch_bounds__(256, 1)
void qfeat_attn_kernel(const float* __restrict__ qk32,
                       const u16* __restrict__ rfh, const u16* __restrict__ rfl,
                       const u16* __restrict__ kvt, const float* __restrict__ ksum,
                       u16* __restrict__ attn_c){
  __shared__ u16 qp[64*264];
  __shared__ u16 lrfh[R_*HD_];
  __shared__ u16 lrfl[R_*HD_];
  __shared__ u16 lkvt[HD_*R_];      // 64 d-rows x 256 r, 32 KB
  const int sc = blockIdx.x, hb = blockIdx.y, h = hb & 15, b = hb >> 4;
  const int tid = threadIdx.x, w = tid >> 6, lane = tid & 63;
  const int q = lane >> 4, rr = lane & 15;
  const int sw8 = rr & 7;
  const float* qbp = qk32 + (size_t)(b*32 + h)*S_*HD_;   // Q head base

  stage_rf_full(rfh, rfl, h, tid, w, lrfh, lrfl);
  // stage kvt[hb] (64 rows x 256 u16 = 512B rows, 32 groups of 16B each):
  // slot gd holds global group gd ^ (row&7); read side XORs identically.
  {
    const u16* kg = kvt + (size_t)hb*HD_*R_;
    #pragma unroll
    for (int c=0;c<8;c++){
      int idx = c*256 + tid;          // 0..2047 <-> (row 0..63, group 0..31)
      int row = idx >> 5, gd = idx & 31;
      int gs  = gd ^ (row & 7);
      gl_lds16(kg + row*256 + gs*8, lkvt + c*2048 + w*512);
    }
  }

  float kslv[16];
  #pragma unroll
  for (int t=0;t<16;t++) kslv[t] = ksum[(size_t)hb*R_ + t*16 + rr];

  __syncthreads();   // rf + kvt staged (drains DMA)

  // preload sub 0's q rows
  const float* ap0 = qbp + (size_t)(sc*1024 + w*16 + rr)*HD_ + q*8;
  float4 x0 = *(const float4*)(ap0);
  float4 x1 = *(const float4*)(ap0 + 4);
  float4 x2 = *(const float4*)(ap0 + 32);
  float4 x3 = *(const float4*)(ap0 + 36);

  for (int sub=0; sub<16; sub++){
    const int s0 = sc*1024 + sub*64;
    // ---- phase 1: q' for 64 s rows ----
    float sql[4];
    rowsq(x0, x1, x2, x3, q, sql);
    short8 ah[2], al[2];
    cvt8(x0, x1, ah[0], al[0]);
    cvt8(x2, x3, ah[1], al[1]);
    if (sub < 15){   // prefetch next sub's q rows (completes under phase 1+2)
      const float* apn = qbp + (size_t)(s0 + 64 + w*16 + rr)*HD_ + q*8;
      x0 = *(const float4*)(apn);
      x1 = *(const float4*)(apn + 4);
      x2 = *(const float4*)(apn + 32);
      x3 = *(const float4*)(apn + 36);
    }

    f32x4 accp[16];
    #pragma unroll
    for (int t=0;t<16;t++) accp[t] = f32x4{0.f,0.f,0.f,0.f};
    #pragma unroll
    for (int t=0;t<16;t++){
      const u16* lrow  = lrfh + (t*16 + rr)*64;
      const u16* lrowl = lrfl + (t*16 + rr)*64;
      short8 bh0 = *(const short8*)(lrow  + ((q     ^ sw8))*8);
      short8 bh1 = *(const short8*)(lrow  + (((q+4) ^ sw8))*8);
      short8 bl0 = *(const short8*)(lrowl + ((q     ^ sw8))*8);
      short8 bl1 = *(const short8*)(lrowl + (((q+4) ^ sw8))*8);
      f32x4 c = accp[t];
      c = mfma16(ah[0], bh0, c); c = mfma16(ah[0], bl0, c); c = mfma16(al[0], bh0, c);
      c = mfma16(ah[1], bh1, c); c = mfma16(ah[1], bl1, c); c = mfma16(al[1], bh1, c);
      accp[t] = c;
    }
    // exp -> qp (A-layout staging) + in-register norm partials
    float npl[4] = {0.f, 0.f, 0.f, 0.f};
    #pragma unroll
    for (int t=0;t<16;t++){
      us4 pk;
      #pragma unroll
      for (int r4=0;r4<4;r4++){
        float e = __expf(accp[t][r4] - sql[r4]);
        npl[r4] += e * kslv[t];
        pk[r4] = f2bf(e);
      }
      #pragma unroll
      for (int r4=0;r4<4;r4++)
        qp[(w*16 + q*4 + r4)*264 + t*16 + rr] = pk[r4];
    }
    // reduce norm over rr (bits 0-3 of lane) -> lanes keep rows q*4+r4
    #pragma unroll
    for (int r4=0;r4<4;r4++){
      npl[r4] += __shfl_xor(npl[r4], 1);
      npl[r4] += __shfl_xor(npl[r4], 2);
      npl[r4] += __shfl_xor(npl[r4], 4);
      npl[r4] += __shfl_xor(npl[r4], 8);
    }
    // no barrier: qp rows read below are the ones this wave just wrote (in-order DS)

    // ---- phase 2: attn = q' @ kv'^T ; wave w owns s rows w*16..w*16+15 ----
    f32x4 acc[4];
    #pragma unroll
    for (int t=0;t<4;t++) acc[t] = f32x4{0.f,0.f,0.f,0.f};
    #pragma unroll
    for (int ks=0; ks<8; ks++){
      short8 af = *(const short8*)(qp + (w*16 + rr)*264 + ks*32 + q*8);
      #pragma unroll
      for (int t=0;t<4;t++){
        short8 bf = *(const short8*)(lkvt + (t*16 + rr)*256 + (((ks*4 + q) ^ sw8))*8);
        acc[t] = mfma16(af, bf, acc[t]);
      }
    }

    #pragma unroll
    for (int t=0;t<4;t++)
      #pragma unroll
      for (int r4=0;r4<4;r4++){
        int sl = w*16 + q*4 + r4;
        int d  = t*16 + rr;
        float o = acc[t][r4] / (npl[r4] + 1e-6f);
        attn_c[((size_t)b*S_ + s0 + sl)*D_ + h*HD_ + d] = f2bf(o);
      }
    // no trailing barrier: next sub's qp writes are same-wave, in-order
  }
}

// ---------------- host ----------------
extern "C" void kernel_launch(void* const* d_in, const int* in_sizes, int n_in,
                              void* d_out, int out_size, void* d_ws, size_t ws_size,
                              hipStream_t stream){
  (void)in_sizes; (void)n_in; (void)out_size; (void)ws_size;
  const float* x  = (const float*)d_in[0];
  const float* wq = (const float*)d_in[1];
  const float* bq = (const float*)d_in[2];
  const float* wk = (const float*)d_in[3];
  const float* bk = (const float*)d_in[4];
  const float* wv = (const float*)d_in[5];
  const float* bv = (const float*)d_in[6];
  const float* wo = (const float*)d_in[7];
  const float* bo = (const float*)d_in[8];
  const float* rf = (const float*)d_in[9];
  float* out = (float*)d_out;

  char* p = (char*)d_ws;
  size_t off = 0;
  auto take = [&](size_t bytes)->char*{
    char* r = p + off; off += (bytes + 255) & ~(size_t)255; return r;
  };
  u16*  x_hi   = (u16*)take((size_t)M_*D_*2);
  u16*  x_lo   = (u16*)take((size_t)M_*D_*2);
  u16*  wqk_hi = (u16*)take((size_t)2*D_*D_*2);   // [wq ; wk] rows 0-2047
  u16*  wqk_lo = (u16*)take((size_t)2*D_*D_*2);
  u16*  wv_hi  = (u16*)take((size_t)D_*D_*2);
  u16*  wo_hi  = (u16*)take((size_t)D_*D_*2);
  u16*  rf_hi  = (u16*)take((size_t)H_*R_*HD_*2);
  u16*  rf_lo  = (u16*)take((size_t)H_*R_*HD_*2);
  float* bqk   = (float*)take((size_t)2048*4);
  float* qk32  = (float*)take((size_t)M_*2048*4); // [b][32 heads][s][hd]
  u16*  v_t    = (u16*)take((size_t)M_*D_*2);
  u16*  kvt    = (u16*)take((size_t)BH_*HD_*R_*2);
  float* ksum  = (float*)take((size_t)BH_*R_*4);
  // aliases (stream-ordered reuse of dead buffers):
  u16* attn_c = x_hi;   // x_hi dead after V projection
  u16* kvp16  = x_lo;   // x_lo dead after fused QK projection; 21 MB <= 33.5 MB

  // prep: all splits + bias concat in ONE launch
  prep_kernel<<<dim3(XB_ + 4*WB_ + 1024 + 8), 256, 0, stream>>>(
      x, wq, wk, wv, wo, rf, bq, bk,
      x_hi, x_lo, wqk_hi, wqk_lo, wv_hi, wo_hi, rf_hi, rf_lo, bqk);

  // fused Q|K projection (N=2048): A-panels read once; L2-locality block swizzle
  gemm128<3,0,1><<<dim3(M_/128, 2048/128), 256, 0, stream>>>(x_hi, x_lo, wqk_hi, wqk_lo, bqk, qk32, nullptr);
  // V projection
  gemm128<1,1,0><<<dim3(M_/128, D_/128), 256, 0, stream>>>(x_hi, nullptr, wv_hi, nullptr, bv, nullptr, v_t);

  // k' -> kv partials (R-split across z) -> reduce
  kfeat_kv_kernel<<<dim3(SPLITK_, BH_, 2), 256, 0, stream>>>(qk32, rf_hi, rf_lo, v_t, kvp16);
  kv_reduce_kernel<<<dim3(R_, BH_), 128, 0, stream>>>(kvp16, kvt, ksum);

  // q' -> attn -> attn_c
  qfeat_attn_kernel<<<dim3(4, BH_), 256, 0, stream>>>(qk32, rf_hi, rf_lo, kvt, ksum, attn_c);

  // output projection
  gemm128<1,2,0><<<dim3(M_/128, D_/128), 256, 0, stream>>>(attn_c, nullptr, wo_hi, nullptr, bo, out, nullptr);
}